// Round 4
// baseline (610.317 us; speedup 1.0000x reference)
//
#include <hip/hip_runtime.h>
#include <math.h>
#include <stddef.h>

// Problem constants
#define BB 2
#define SS 512
#define DD 768
#define HH 12
#define HDIM 64
#define EE 50
#define DE 50
#define F1 128

typedef float f32x4 __attribute__((ext_vector_type(4)));
typedef short s16x8 __attribute__((ext_vector_type(8)));

// f32 -> bf16 bits, round-to-nearest-even
static __device__ __forceinline__ unsigned short f2bf(float x) {
  unsigned int u = __float_as_uint(x);
  unsigned int r = u + 0x7fffu + ((u >> 16) & 1u);
  return (unsigned short)(r >> 16);
}
static __device__ __forceinline__ float bf2f(unsigned short b) {
  return __uint_as_float(((unsigned int)b) << 16);
}

// ---------------------------------------------------------------------------
// Generic tiled f32 GEMM: Y[m][n] = sum_k X[m][k] * W[n][k] + bias[n]
// ---------------------------------------------------------------------------
__global__ __launch_bounds__(256) void k_gemm_bias(
    const float* __restrict__ X, int ldx,
    const float* __restrict__ W,   // [N][K] row-major
    const float* __restrict__ bias,
    float* __restrict__ Y, int ldy,
    int M, int N, int K)
{
  __shared__ float Xs[32][68];
  __shared__ float Ws[32][68];
  int t = threadIdx.x;
  int tx = t & 15, ty = t >> 4;
  int m0 = blockIdx.y * 64, n0 = blockIdx.x * 64;
  float acc[4][4] = {};
  for (int k0 = 0; k0 < K; k0 += 32) {
#pragma unroll
    for (int q = 0; q < 2; ++q) {
      int idx = t + q * 256;
      int r = idx >> 3, c = (idx & 7) << 2;
      float4 v = *(const float4*)(X + (size_t)(m0 + r) * ldx + k0 + c);
      Xs[c + 0][r] = v.x; Xs[c + 1][r] = v.y; Xs[c + 2][r] = v.z; Xs[c + 3][r] = v.w;
      float4 w = *(const float4*)(W + (size_t)(n0 + r) * K + k0 + c);
      Ws[c + 0][r] = w.x; Ws[c + 1][r] = w.y; Ws[c + 2][r] = w.z; Ws[c + 3][r] = w.w;
    }
    __syncthreads();
#pragma unroll
    for (int kk = 0; kk < 32; ++kk) {
      float a[4], b[4];
#pragma unroll
      for (int u = 0; u < 4; ++u) a[u] = Xs[kk][ty * 4 + u];
#pragma unroll
      for (int u = 0; u < 4; ++u) b[u] = Ws[kk][tx * 4 + u];
#pragma unroll
      for (int i = 0; i < 4; ++i)
#pragma unroll
        for (int j = 0; j < 4; ++j) acc[i][j] += a[i] * b[j];
    }
    __syncthreads();
  }
#pragma unroll
  for (int i = 0; i < 4; ++i) {
    int m = m0 + ty * 4 + i;
#pragma unroll
    for (int j = 0; j < 4; ++j) {
      int n = n0 + tx * 4 + j;
      Y[(size_t)m * ldy + n] = acc[i][j] + bias[n];
    }
  }
}

// ---------------------------------------------------------------------------
// attn_src[b,h,s], attn_dst[b,h,s]
// ---------------------------------------------------------------------------
__global__ __launch_bounds__(192) void k_attnvec(
    const float* __restrict__ feat, const float* __restrict__ w1,
    const float* __restrict__ w2, float* __restrict__ src, float* __restrict__ dst)
{
  int bs = blockIdx.x;
  int t = threadIdx.x;
  int h = t >> 4, l = t & 15;
  float4 f = *(const float4*)(feat + (size_t)bs * DD + h * HDIM + l * 4);
  float4 a = *(const float4*)(w1 + h * HDIM + l * 4);
  float4 c = *(const float4*)(w2 + h * HDIM + l * 4);
  float ps = f.x * a.x + f.y * a.y + f.z * a.z + f.w * a.w;
  float pd = f.x * c.x + f.y * c.y + f.z * c.z + f.w * c.w;
#pragma unroll
  for (int o = 8; o > 0; o >>= 1) {
    ps += __shfl_xor(ps, o);
    pd += __shfl_xor(pd, o);
  }
  if (l == 0) {
    int b = bs >> 9, s = bs & 511;
    src[((b * HH + h) << 9) + s] = ps;
    dst[((b * HH + h) << 9) + s] = pd;
  }
}

// ---------------------------------------------------------------------------
// MFMA fused edge-MLP -> attention scores. ONE BLOCK PER (b, i, j-chunk of
// 128): 4096 independent blocks, 3 blocks/CU (52.7 KB LDS) -> HBM latency of
// one block hides under compute of its CU neighbors. Weights in registers.
// 256 threads = 4 waves; wave w owns j-rows [w*32, w*32+32).
// scores layout: [b][i][h][j]
// ---------------------------------------------------------------------------
__global__ __launch_bounds__(256, 3) void k_scores_mfma(
    const float* __restrict__ wprob, const float* __restrict__ sloop,
    const float* __restrict__ We1, const float* __restrict__ be1,
    const float* __restrict__ We2, const float* __restrict__ be2,
    const float* __restrict__ src, const float* __restrict__ dst,
    float* __restrict__ scores)
{
  __shared__ unsigned short wps_s[128][72];    // [j][e] bf16, 18.4 KB
  __shared__ unsigned short hmid_s[128][132];  // [j][f] bf16, 33.8 KB
  __shared__ float masks[128];

  const int blk = blockIdx.x;        // (b*512 + i)*4 + c
  const int c = blk & 3;
  const int i = (blk >> 2) & 511;
  const int b = blk >> 11;
  const int j0c = c << 7;
  const int t = threadIdx.x;
  const int w = t >> 6, l = t & 63;
  const int lr = l & 15, lg = l >> 4;
  const int jbase = w * 32;

  // ---- issue the HBM loads for this chunk FIRST (28 float4/thread) ----
  const size_t rowbase = (size_t)(b * SS + i) * SS * EE + (size_t)c * 6400;
  float4 pw[7], psl[7];
  {
    const float* wp = wprob + rowbase;
    const float* sl = sloop + rowbase;
#pragma unroll
    for (int k = 0; k < 7; ++k)
      if (k < 6 || t < 64) {
        pw[k] = *(const float4*)(wp + 4 * (t + 256 * k));
        psl[k] = *(const float4*)(sl + 4 * (t + 256 * k));
      }
  }

  // ---- weight fragments to registers (L2-resident, hidden under wps) ----
  s16x8 wa[2][8];   // We1 B-frags [ks][n]: f = n*16+lr, e = ks*32+lg*8+u
#pragma unroll
  for (int ks = 0; ks < 2; ++ks)
#pragma unroll
    for (int n = 0; n < 8; ++n)
#pragma unroll
      for (int u = 0; u < 8; ++u) {
        int e = ks * 32 + lg * 8 + u;
        float v = (e < 50) ? We1[(n * 16 + lr) * 50 + e] : 0.0f;
        wa[ks][n][u] = (short)f2bf(v);
      }
  s16x8 wb[4];      // We2 B-frags [kk]: h = lr, f = kk*32+lg*8+u
#pragma unroll
  for (int kk = 0; kk < 4; ++kk)
#pragma unroll
    for (int u = 0; u < 8; ++u) {
      int f = kk * 32 + lg * 8 + u;
      wb[kk][u] = (short)((lr < 12) ? f2bf(We2[lr * 128 + f]) : (unsigned short)0);
    }
  float be1v[8];
#pragma unroll
  for (int n = 0; n < 8; ++n) be1v[n] = be1[n * 16 + lr];
  const int hc = (lr < 12) ? lr : 0;
  const float be2v = be2[hc];
  const float srcv = src[((b * HH + hc) << 9) + i];
  const float* drow = dst + ((size_t)(b * HH + hc) << 9);
  float4 dv0 = *(const float4*)(drow + j0c + jbase + lg * 4);
  float4 dv1 = *(const float4*)(drow + j0c + jbase + 16 + lg * 4);

  // zero pad cols e=50..63 (dwords 25..31 of each 36-dword row)
  for (int q = t; q < 896; q += 256) {
    int r = q / 7, cd = 25 + q % 7;
    ((unsigned int*)wps_s)[r * 36 + cd] = 0u;
  }

  // ---- LDS write (waits on wps loads) ----
#pragma unroll
  for (int k = 0; k < 7; ++k)
    if (k < 6 || t < 64) {
      int f = 4 * (t + 256 * k);
      int j = f / 50;
      int e0 = f - j * 50;
      float vs[4] = {pw[k].x + psl[k].x, pw[k].y + psl[k].y,
                     pw[k].z + psl[k].z, pw[k].w + psl[k].w};
#pragma unroll
      for (int u = 0; u < 4; ++u) {
        int e = e0 + u, jj = j;
        if (e >= 50) { e -= 50; jj += 1; }
        wps_s[jj][e] = f2bf(vs[u]);
      }
    }
  __syncthreads();

  // per-wave masks for own j-rows (wave-local write+read; no extra barrier)
  if (l < 32) {
    const unsigned short* row = wps_s[jbase + l];
    float s = 0.0f;
#pragma unroll
    for (int q = 0; q < 6; ++q) {
      s16x8 v = *(const s16x8*)(row + q * 8);
#pragma unroll
      for (int u = 0; u < 8; ++u) s += bf2f((unsigned short)v[u]);
    }
    unsigned int last = *(const unsigned int*)(row + 48);
    s += bf2f((unsigned short)(last & 0xffffu)) + bf2f((unsigned short)(last >> 16));
    masks[jbase + l] = (s == 0.0f) ? 1.0f : 0.0f;
  }

  // ---- stage A: hmid = relu(wps @ We1^T + be1) ----
  f32x4 accA[2][8] = {};
#pragma unroll
  for (int ks = 0; ks < 2; ++ks) {
    s16x8 a0 = *(const s16x8*)&wps_s[jbase + lr][ks * 32 + lg * 8];
    s16x8 a1 = *(const s16x8*)&wps_s[jbase + 16 + lr][ks * 32 + lg * 8];
#pragma unroll
    for (int n = 0; n < 8; ++n) {
      accA[0][n] = __builtin_amdgcn_mfma_f32_16x16x32_bf16(a0, wa[ks][n], accA[0][n], 0, 0, 0);
      accA[1][n] = __builtin_amdgcn_mfma_f32_16x16x32_bf16(a1, wa[ks][n], accA[1][n], 0, 0, 0);
    }
  }
#pragma unroll
  for (int jt = 0; jt < 2; ++jt)
#pragma unroll
    for (int n = 0; n < 8; ++n)
#pragma unroll
      for (int r = 0; r < 4; ++r) {
        float v = fmaxf(accA[jt][n][r] + be1v[n], 0.0f);
        hmid_s[jbase + jt * 16 + lg * 4 + r][n * 16 + lr] = f2bf(v);
      }

  // ---- stage B: A = hmid @ We2^T (wave-local rows; no barrier) ----
  f32x4 accB[2] = {};
#pragma unroll
  for (int kk = 0; kk < 4; ++kk) {
    s16x8 a0 = *(const s16x8*)&hmid_s[jbase + lr][kk * 32 + lg * 8];
    s16x8 a1 = *(const s16x8*)&hmid_s[jbase + 16 + lr][kk * 32 + lg * 8];
    accB[0] = __builtin_amdgcn_mfma_f32_16x16x32_bf16(a0, wb[kk], accB[0], 0, 0, 0);
    accB[1] = __builtin_amdgcn_mfma_f32_16x16x32_bf16(a1, wb[kk], accB[1], 0, 0, 0);
  }

  // ---- epilogue: leaky-relu + mask, direct float4 stores ----
  if (lr < 12) {
#pragma unroll
    for (int jt = 0; jt < 2; ++jt) {
      int jl = jbase + jt * 16 + lg * 4;   // local j of r=0 (4-aligned)
      const float4 dv = jt ? dv1 : dv0;
      float4 st;
#pragma unroll
      for (int r = 0; r < 4; ++r) {
        float x = accB[jt][r] + be2v + srcv + (&dv.x)[r];
        x = (x > 0.0f) ? x : 0.01f * x;
        if (masks[jl + r] != 0.0f) x = -INFINITY;
        (&st.x)[r] = x;
      }
      *(float4*)(scores + ((((size_t)(b * SS + i)) * HH + lr) << 9) + j0c + jl) = st;
    }
  }
}

// ---------------------------------------------------------------------------
// Softmax over j (per b,i,h) + PV: gcnmid[b,i,:] = sum_j attn * feature[b,j,:]
// ---------------------------------------------------------------------------
__global__ __launch_bounds__(256) void k_softmax_pv(
    const float* __restrict__ scores, const float* __restrict__ feat,
    float* __restrict__ gout)
{
  __shared__ float p[2][12][512];
  int blk = blockIdx.x;
  int b = blk >> 8;
  int i0 = (blk & 255) << 1;
  int t = threadIdx.x;
  size_t base = ((size_t)(b * SS + i0) * HH) << 9;
  for (int q = t; q < 12288; q += 256) ((float*)p)[q] = scores[base + q];
  __syncthreads();

  int w = t >> 6, l = t & 63;
  for (int r = w; r < 24; r += 4) {
    int ii = r / 12, h = r % 12;
    float* row = p[ii][h];
    float vv[8];
    float m = -INFINITY;
#pragma unroll
    for (int u = 0; u < 8; ++u) {
      vv[u] = row[l + (u << 6)];
      m = fmaxf(m, vv[u]);
    }
#pragma unroll
    for (int o = 32; o > 0; o >>= 1) m = fmaxf(m, __shfl_xor(m, o));
    float s = 0.0f;
#pragma unroll
    for (int u = 0; u < 8; ++u) {
      float e = __expf(vv[u] - m);
      vv[u] = e;
      s += e;
    }
#pragma unroll
    for (int o = 32; o > 0; o >>= 1) s += __shfl_xor(s, o);
    float inv = 1.0f / s;
#pragma unroll
    for (int u = 0; u < 8; ++u) row[l + (u << 6)] = vv[u] * inv;
  }
  __syncthreads();

  float acc[2][3] = {};
  const float* fb = feat + (size_t)b * SS * DD;
  int h0 = t >> 6;
#pragma unroll 4
  for (int j = 0; j < 512; ++j) {
    const float* fr = fb + (size_t)j * DD;
    float f0 = fr[t], f1 = fr[t + 256], f2 = fr[t + 512];
    float p00 = p[0][h0][j], p10 = p[1][h0][j];
    float p01 = p[0][h0 + 4][j], p11 = p[1][h0 + 4][j];
    float p02 = p[0][h0 + 8][j], p12 = p[1][h0 + 8][j];
    acc[0][0] += p00 * f0; acc[0][1] += p01 * f1; acc[0][2] += p02 * f2;
    acc[1][0] += p10 * f0; acc[1][1] += p11 * f1; acc[1][2] += p12 * f2;
  }
#pragma unroll
  for (int ii = 0; ii < 2; ++ii)
#pragma unroll
    for (int u = 0; u < 3; ++u)
      gout[(size_t)(b * SS + i0 + ii) * DD + t + (u << 8)] = acc[ii][u];
}

// ---------------------------------------------------------------------------
// LayerNorm (torch variant: unbiased std, /(std+eps)) + ReLU -> node (d_out)
// ---------------------------------------------------------------------------
__global__ __launch_bounds__(256) void k_ln(
    const float* __restrict__ gcn2, const float* __restrict__ ga,
    const float* __restrict__ gb, float* __restrict__ out)
{
  __shared__ float rs[4], rss[4];
  int row = blockIdx.x;
  int t = threadIdx.x;
  const float* x = gcn2 + (size_t)row * DD;
  float v[3];
  float s = 0.0f, ss2 = 0.0f;
#pragma unroll
  for (int u = 0; u < 3; ++u) {
    v[u] = x[t + (u << 8)];
    s += v[u];
    ss2 += v[u] * v[u];
  }
#pragma unroll
  for (int o = 32; o > 0; o >>= 1) {
    s += __shfl_down(s, o);
    ss2 += __shfl_down(ss2, o);
  }
  int w = t >> 6, l = t & 63;
  if (l == 0) { rs[w] = s; rss[w] = ss2; }
  __syncthreads();
  float S = rs[0] + rs[1] + rs[2] + rs[3];
  float SSum = rss[0] + rss[1] + rss[2] + rss[3];
  float mean = S * (1.0f / 768.0f);
  float var = (SSum - 768.0f * mean * mean) * (1.0f / 767.0f);
  var = fmaxf(var, 0.0f);
  float rinv = 1.0f / (sqrtf(var) + 1e-6f);
#pragma unroll
  for (int u = 0; u < 3; ++u) {
    int cidx = t + (u << 8);
    float y = ga[cidx] * (v[u] - mean) * rinv + gb[cidx];
    out[(size_t)row * DD + cidx] = fmaxf(y, 0.0f);
  }
}

// ---------------------------------------------------------------------------
// P[b,s,f] = ediag[b,s]@Wh_ei^T + node[b,s]@Wh_n2^T
// Q[b,s,f] = ediag[b,s]@Wh_ej^T + node[b,s]@Wh_n1^T + bh
// 512 threads: (which, f, d-quadrant) per thread, shfl-reduce over quadrant.
// ---------------------------------------------------------------------------
__global__ __launch_bounds__(512) void k_pq(
    const float* __restrict__ node, const float* __restrict__ wadj,
    const float* __restrict__ Whei, const float* __restrict__ Whej,
    const float* __restrict__ Whn1, const float* __restrict__ Whn2,
    const float* __restrict__ bh, float* __restrict__ P, float* __restrict__ Q)
{
  __shared__ float nd[768];
  __shared__ float ed[50];
  int bs = blockIdx.x;
  int b = bs >> 9, s = bs & 511;
  int t = threadIdx.x;
  for (int q = t; q < 768; q += 512) nd[q] = node[(size_t)bs * DD + q];
  if (t < 50) ed[t] = wadj[((size_t)(b * SS + s) * SS + s) * EE + t];
  __syncthreads();
  int which = t >> 8;
  int r = t & 255;
  int f = r >> 2, dq = r & 3;
  if (f < 50) {
    const float* Wn = which ? Whn1 : Whn2;
    float acc = 0.0f;
    const float* wrow = Wn + f * DD + dq * 192;
    const float* ndp = nd + dq * 192;
#pragma unroll 4
    for (int d = 0; d < 192; ++d) acc += ndp[d] * wrow[d];
    if (dq == 0) {
      const float* We = which ? Whej : Whei;
      for (int e = 0; e < 50; ++e) acc += ed[e] * We[f * EE + e];
    }
    acc += __shfl_xor(acc, 1);
    acc += __shfl_xor(acc, 2);
    if (dq == 0) {
      float outv = acc + (which ? bh[f] : 0.0f);
      (which ? Q : P)[(size_t)bs * DE + f] = outv;
    }
  }
}

// ---------------------------------------------------------------------------
// edge_out[n,f] = wadj[n,:]@Wh_e[f,:] + P[b,i,f] + Q[b,j,f]
// Compute in regs, park tile in LDS (aliased over adjs), stream float4 out.
// ---------------------------------------------------------------------------
__global__ __launch_bounds__(256) void k_edge(
    const float* __restrict__ wadj, const float* __restrict__ Whe,
    const float* __restrict__ P, const float* __restrict__ Q,
    float* __restrict__ eout)
{
  __shared__ float adjs[128][51];
  __shared__ float whes[52][52];
  int t = threadIdx.x;
  size_t n0 = (size_t)blockIdx.x * 128;
  for (int q = t; q < 2500; q += 256) whes[q / 50][q % 50] = Whe[q];
  for (int q = t; q < 52 * 52 - 2600; q += 256) {
    int qq = q + 2600;
    whes[qq / 52][qq % 52] = 0.0f;
  }
  for (int q = t; q < 6400; q += 256) adjs[q / 50][q % 50] = wadj[n0 * EE + q];
  __syncthreads();

  int pl = t & 31;
  int fg = t >> 5;
  int f0 = fg < 2 ? fg * 7 : 14 + (fg - 2) * 6;
  int nf = fg < 2 ? 7 : 6;
  float acc[4][7] = {};
  for (int e = 0; e < 50; ++e) {
    float aw[7];
#pragma unroll
    for (int u = 0; u < 7; ++u) aw[u] = whes[f0 + u][e];
    float ap0 = adjs[pl][e], ap1 = adjs[pl + 32][e];
    float ap2 = adjs[pl + 64][e], ap3 = adjs[pl + 96][e];
#pragma unroll
    for (int u = 0; u < 7; ++u) {
      acc[0][u] += ap0 * aw[u];
      acc[1][u] += ap1 * aw[u];
      acc[2][u] += ap2 * aw[u];
      acc[3][u] += ap3 * aw[u];
    }
  }
  // finalize with P (block-row-uniform) and Q (per-j) in registers
  float fin[4][7];
#pragma unroll
  for (int pp = 0; pp < 4; ++pp) {
    size_t n = n0 + pl + 32 * pp;
    int b = (int)(n >> 18);
    int rem = (int)(n & 262143);
    int i = rem >> 9, j = rem & 511;
    const float* Pr = P + (size_t)(b * SS + i) * DE;
    const float* Qr = Q + (size_t)(b * SS + j) * DE;
    for (int u = 0; u < nf; ++u) {
      int f = f0 + u;
      fin[pp][u] = acc[pp][u] + Pr[f] + Qr[f];
    }
  }
  __syncthreads();  // everyone done reading adjs
  float* outs = &adjs[0][0];  // 6400-float tile, flat
#pragma unroll
  for (int pp = 0; pp < 4; ++pp)
    for (int u = 0; u < nf; ++u)
      outs[(pl + 32 * pp) * 50 + f0 + u] = fin[pp][u];
  __syncthreads();
  const float4* src4 = (const float4*)outs;
  float4* dst4 = (float4*)(eout + n0 * DE);
  for (int q = t; q < 1600; q += 256) dst4[q] = src4[q];
}

// ---------------------------------------------------------------------------
extern "C" void kernel_launch(void* const* d_in, const int* in_sizes, int n_in,
                              void* d_out, int out_size, void* d_ws, size_t ws_size,
                              hipStream_t stream)
{
  const float* wprob = (const float*)d_in[0];
  const float* wadj  = (const float*)d_in[1];
  const float* gin   = (const float*)d_in[2];
  const float* sloop = (const float*)d_in[3];
  const float* W_lin = (const float*)d_in[4];
  const float* b_lin = (const float*)d_in[5];
  const float* fw1   = (const float*)d_in[6];
  const float* fw2   = (const float*)d_in[7];
  const float* We1   = (const float*)d_in[8];
  const float* be1   = (const float*)d_in[9];
  const float* We2   = (const float*)d_in[10];
  const float* be2   = (const float*)d_in[11];
  const float* W_out = (const float*)d_in[12];
  const float* b_out = (const float*)d_in[13];
  const float* ln_a  = (const float*)d_in[14];
  const float* ln_b  = (const float*)d_in[15];
  const float* Whe   = (const float*)d_in[16];
  const float* Whei  = (const float*)d_in[17];
  const float* Whej  = (const float*)d_in[18];
  const float* Whn1  = (const float*)d_in[19];
  const float* Whn2  = (const float*)d_in[20];
  const float* bh    = (const float*)d_in[21];

  float* ws = (float*)d_ws;
  float* feature = ws + 0;         // [B,S,D]      786432
  float* src     = ws + 786432;    // [B,H,S]      12288
  float* dst     = ws + 798720;    // [B,H,S]      12288
  float* scores  = ws + 811008;    // [B,S,H,S]    6291456
  float* gcnmid  = ws + 7102464;   // [B,S,D]      786432
  float* gcn2    = ws + 7888896;   // [B,S,D]      786432
  float* P       = ws + 8675328;   // [B,S,DE]     51200
  float* Q       = ws + 8726528;   // [B,S,DE]     51200

  float* node = (float*)d_out;            // output 0: [B,S,D]
  float* eout = (float*)d_out + 786432;   // output 1: [B,S,S,DE]

  k_gemm_bias<<<dim3(DD / 64, (BB * SS) / 64), 256, 0, stream>>>(
      gin, DD, W_lin, b_lin, feature, DD, BB * SS, DD, DD);
  k_attnvec<<<BB * SS, 192, 0, stream>>>(feature, fw1, fw2, src, dst);
  k_scores_mfma<<<BB * SS * 4, 256, 0, stream>>>(
      wprob, sloop, We1, be1, We2, be2, src, dst, scores);
  k_softmax_pv<<<BB * SS / 2, 256, 0, stream>>>(scores, feature, gcnmid);
  k_gemm_bias<<<dim3(DD / 64, (BB * SS) / 64), 256, 0, stream>>>(
      gcnmid, DD, W_out, b_out, gcn2, DD, BB * SS, DD, DD);
  k_ln<<<BB * SS, 256, 0, stream>>>(gcn2, ln_a, ln_b, node);
  k_pq<<<BB * SS, 512, 0, stream>>>(node, wadj, Whei, Whej, Whn1, Whn2, bh, P, Q);
  k_edge<<<(BB * SS * SS) / 128, 256, 0, stream>>>(wadj, Whe, P, Q, eout);
}

// Round 5
// 394.351 us; speedup vs baseline: 1.5476x; 1.5476x over previous
//
#include <hip/hip_runtime.h>
#include <math.h>
#include <stddef.h>

// Problem constants
#define BB 2
#define SS 512
#define DD 768
#define HH 12
#define HDIM 64
#define EE 50
#define DE 50
#define F1 128

typedef float f32x4 __attribute__((ext_vector_type(4)));
typedef short s16x8 __attribute__((ext_vector_type(8)));

// f32 -> bf16 bits, round-to-nearest-even
static __device__ __forceinline__ unsigned short f2bf(float x) {
  unsigned int u = __float_as_uint(x);
  unsigned int r = u + 0x7fffu + ((u >> 16) & 1u);
  return (unsigned short)(r >> 16);
}
static __device__ __forceinline__ float bf2f(unsigned short b) {
  return __uint_as_float(((unsigned int)b) << 16);
}

// ---------------------------------------------------------------------------
// Generic tiled f32 GEMM: Y[m][n] = sum_k X[m][k] * W[n][k] + bias[n]
// ---------------------------------------------------------------------------
__global__ __launch_bounds__(256) void k_gemm_bias(
    const float* __restrict__ X, int ldx,
    const float* __restrict__ W,   // [N][K] row-major
    const float* __restrict__ bias,
    float* __restrict__ Y, int ldy,
    int M, int N, int K)
{
  __shared__ float Xs[32][68];
  __shared__ float Ws[32][68];
  int t = threadIdx.x;
  int tx = t & 15, ty = t >> 4;
  int m0 = blockIdx.y * 64, n0 = blockIdx.x * 64;
  float acc[4][4] = {};
  for (int k0 = 0; k0 < K; k0 += 32) {
#pragma unroll
    for (int q = 0; q < 2; ++q) {
      int idx = t + q * 256;
      int r = idx >> 3, c = (idx & 7) << 2;
      float4 v = *(const float4*)(X + (size_t)(m0 + r) * ldx + k0 + c);
      Xs[c + 0][r] = v.x; Xs[c + 1][r] = v.y; Xs[c + 2][r] = v.z; Xs[c + 3][r] = v.w;
      float4 w = *(const float4*)(W + (size_t)(n0 + r) * K + k0 + c);
      Ws[c + 0][r] = w.x; Ws[c + 1][r] = w.y; Ws[c + 2][r] = w.z; Ws[c + 3][r] = w.w;
    }
    __syncthreads();
#pragma unroll
    for (int kk = 0; kk < 32; ++kk) {
      float a[4], b[4];
#pragma unroll
      for (int u = 0; u < 4; ++u) a[u] = Xs[kk][ty * 4 + u];
#pragma unroll
      for (int u = 0; u < 4; ++u) b[u] = Ws[kk][tx * 4 + u];
#pragma unroll
      for (int i = 0; i < 4; ++i)
#pragma unroll
        for (int j = 0; j < 4; ++j) acc[i][j] += a[i] * b[j];
    }
    __syncthreads();
  }
#pragma unroll
  for (int i = 0; i < 4; ++i) {
    int m = m0 + ty * 4 + i;
#pragma unroll
    for (int j = 0; j < 4; ++j) {
      int n = n0 + tx * 4 + j;
      Y[(size_t)m * ldy + n] = acc[i][j] + bias[n];
    }
  }
}

// ---------------------------------------------------------------------------
// attn_src[b,h,s], attn_dst[b,h,s]
// ---------------------------------------------------------------------------
__global__ __launch_bounds__(192) void k_attnvec(
    const float* __restrict__ feat, const float* __restrict__ w1,
    const float* __restrict__ w2, float* __restrict__ src, float* __restrict__ dst)
{
  int bs = blockIdx.x;
  int t = threadIdx.x;
  int h = t >> 4, l = t & 15;
  float4 f = *(const float4*)(feat + (size_t)bs * DD + h * HDIM + l * 4);
  float4 a = *(const float4*)(w1 + h * HDIM + l * 4);
  float4 c = *(const float4*)(w2 + h * HDIM + l * 4);
  float ps = f.x * a.x + f.y * a.y + f.z * a.z + f.w * a.w;
  float pd = f.x * c.x + f.y * c.y + f.z * c.z + f.w * c.w;
#pragma unroll
  for (int o = 8; o > 0; o >>= 1) {
    ps += __shfl_xor(ps, o);
    pd += __shfl_xor(pd, o);
  }
  if (l == 0) {
    int b = bs >> 9, s = bs & 511;
    src[((b * HH + h) << 9) + s] = ps;
    dst[((b * HH + h) << 9) + s] = pd;
  }
}

// ---------------------------------------------------------------------------
// Precompute per-lane MFMA weight fragments (lane-only dependent, 64 variants)
// wtab[k][lane] : s16x8;  k = ks*8+n (We1 frags, 0..15), 16+kk (We2, 16..19)
// betab[n][lane]: f32     be1[n*16 + (lane&15)]
// One wave; runs in ~1 us. Table is 20*64*16 + 8*64*4 = 22.5 KB, L2-resident.
// ---------------------------------------------------------------------------
__global__ __launch_bounds__(64) void k_prep(
    const float* __restrict__ We1, const float* __restrict__ be1,
    const float* __restrict__ We2,
    s16x8* __restrict__ wtab, float* __restrict__ betab)
{
  const int l = threadIdx.x;
  const int lr = l & 15, lg = l >> 4;
#pragma unroll
  for (int ks = 0; ks < 2; ++ks)
#pragma unroll
    for (int n = 0; n < 8; ++n) {
      s16x8 v;
#pragma unroll
      for (int u = 0; u < 8; ++u) {
        int e = ks * 32 + lg * 8 + u;
        float x = (e < 50) ? We1[(n * 16 + lr) * 50 + e] : 0.0f;
        v[u] = (short)f2bf(x);
      }
      wtab[(ks * 8 + n) * 64 + l] = v;
    }
#pragma unroll
  for (int kk = 0; kk < 4; ++kk) {
    s16x8 v;
#pragma unroll
    for (int u = 0; u < 8; ++u) {
      int f = kk * 32 + lg * 8 + u;
      v[u] = (short)((lr < 12) ? f2bf(We2[lr * 128 + f]) : (unsigned short)0);
    }
    wtab[(16 + kk) * 64 + l] = v;
  }
#pragma unroll
  for (int n = 0; n < 8; ++n) betab[n * 64 + l] = be1[n * 16 + lr];
}

// ---------------------------------------------------------------------------
// MFMA fused edge-MLP -> attention scores. One block per (b, i, j-chunk of
// 128): 4096 independent blocks, 3 blocks/CU. Weight fragments come from the
// precomputed lane table (20 coalesced 16B loads, L2-resident).
// 256 threads = 4 waves; wave w owns j-rows [w*32, w*32+32).
// scores layout: [b][i][h][j]
// ---------------------------------------------------------------------------
__global__ __launch_bounds__(256, 3) void k_scores_mfma(
    const float* __restrict__ wprob, const float* __restrict__ sloop,
    const s16x8* __restrict__ wtab, const float* __restrict__ betab,
    const float* __restrict__ be2,
    const float* __restrict__ src, const float* __restrict__ dst,
    float* __restrict__ scores)
{
  __shared__ unsigned short wps_s[128][72];    // [j][e] bf16, 18.4 KB
  __shared__ unsigned short hmid_s[128][132];  // [j][f] bf16, 33.8 KB
  __shared__ float masks[128];

  const int blk = blockIdx.x;        // (b*512 + i)*4 + c
  const int c = blk & 3;
  const int i = (blk >> 2) & 511;
  const int b = blk >> 11;
  const int j0c = c << 7;
  const int t = threadIdx.x;
  const int w = t >> 6, l = t & 63;
  const int lr = l & 15, lg = l >> 4;
  const int jbase = w * 32;

  // ---- issue the HBM loads for this chunk FIRST (28 float4/thread) ----
  const size_t rowbase = (size_t)(b * SS + i) * SS * EE + (size_t)c * 6400;
  float4 pw[7], psl[7];
  {
    const float* wp = wprob + rowbase;
    const float* sl = sloop + rowbase;
#pragma unroll
    for (int k = 0; k < 7; ++k)
      if (k < 6 || t < 64) {
        pw[k] = *(const float4*)(wp + 4 * (t + 256 * k));
        psl[k] = *(const float4*)(sl + 4 * (t + 256 * k));
      }
  }

  // ---- weight fragments from lane table (coalesced, L2-resident) ----
  s16x8 wa[2][8];
#pragma unroll
  for (int ks = 0; ks < 2; ++ks)
#pragma unroll
    for (int n = 0; n < 8; ++n) wa[ks][n] = wtab[(ks * 8 + n) * 64 + l];
  s16x8 wb[4];
#pragma unroll
  for (int kk = 0; kk < 4; ++kk) wb[kk] = wtab[(16 + kk) * 64 + l];
  float be1v[8];
#pragma unroll
  for (int n = 0; n < 8; ++n) be1v[n] = betab[n * 64 + l];
  const int hc = (lr < 12) ? lr : 0;
  const float be2v = be2[hc];
  const float srcv = src[((b * HH + hc) << 9) + i];
  const float* drow = dst + ((size_t)(b * HH + hc) << 9);
  float4 dv0 = *(const float4*)(drow + j0c + jbase + lg * 4);
  float4 dv1 = *(const float4*)(drow + j0c + jbase + 16 + lg * 4);

  // zero pad cols e=50..63 (dwords 25..31 of each 36-dword row)
  for (int q = t; q < 896; q += 256) {
    int r = q / 7, cd = 25 + q % 7;
    ((unsigned int*)wps_s)[r * 36 + cd] = 0u;
  }

  // ---- LDS write (waits on wps loads) ----
#pragma unroll
  for (int k = 0; k < 7; ++k)
    if (k < 6 || t < 64) {
      int f = 4 * (t + 256 * k);
      int j = f / 50;
      int e0 = f - j * 50;
      float vs[4] = {pw[k].x + psl[k].x, pw[k].y + psl[k].y,
                     pw[k].z + psl[k].z, pw[k].w + psl[k].w};
#pragma unroll
      for (int u = 0; u < 4; ++u) {
        int e = e0 + u, jj = j;
        if (e >= 50) { e -= 50; jj += 1; }
        wps_s[jj][e] = f2bf(vs[u]);
      }
    }
  __syncthreads();

  // per-wave masks for own j-rows (wave-local write+read; no extra barrier)
  if (l < 32) {
    const unsigned short* row = wps_s[jbase + l];
    float s = 0.0f;
#pragma unroll
    for (int q = 0; q < 6; ++q) {
      s16x8 v = *(const s16x8*)(row + q * 8);
#pragma unroll
      for (int u = 0; u < 8; ++u) s += bf2f((unsigned short)v[u]);
    }
    unsigned int last = *(const unsigned int*)(row + 48);
    s += bf2f((unsigned short)(last & 0xffffu)) + bf2f((unsigned short)(last >> 16));
    masks[jbase + l] = (s == 0.0f) ? 1.0f : 0.0f;
  }

  // ---- stage A: hmid = relu(wps @ We1^T + be1) ----
  f32x4 accA[2][8] = {};
#pragma unroll
  for (int ks = 0; ks < 2; ++ks) {
    s16x8 a0 = *(const s16x8*)&wps_s[jbase + lr][ks * 32 + lg * 8];
    s16x8 a1 = *(const s16x8*)&wps_s[jbase + 16 + lr][ks * 32 + lg * 8];
#pragma unroll
    for (int n = 0; n < 8; ++n) {
      accA[0][n] = __builtin_amdgcn_mfma_f32_16x16x32_bf16(a0, wa[ks][n], accA[0][n], 0, 0, 0);
      accA[1][n] = __builtin_amdgcn_mfma_f32_16x16x32_bf16(a1, wa[ks][n], accA[1][n], 0, 0, 0);
    }
  }
#pragma unroll
  for (int jt = 0; jt < 2; ++jt)
#pragma unroll
    for (int n = 0; n < 8; ++n)
#pragma unroll
      for (int r = 0; r < 4; ++r) {
        float v = fmaxf(accA[jt][n][r] + be1v[n], 0.0f);
        hmid_s[jbase + jt * 16 + lg * 4 + r][n * 16 + lr] = f2bf(v);
      }

  // ---- stage B: A = hmid @ We2^T (wave-local rows; no barrier) ----
  f32x4 accB[2] = {};
#pragma unroll
  for (int kk = 0; kk < 4; ++kk) {
    s16x8 a0 = *(const s16x8*)&hmid_s[jbase + lr][kk * 32 + lg * 8];
    s16x8 a1 = *(const s16x8*)&hmid_s[jbase + 16 + lr][kk * 32 + lg * 8];
    accB[0] = __builtin_amdgcn_mfma_f32_16x16x32_bf16(a0, wb[kk], accB[0], 0, 0, 0);
    accB[1] = __builtin_amdgcn_mfma_f32_16x16x32_bf16(a1, wb[kk], accB[1], 0, 0, 0);
  }

  // ---- epilogue: leaky-relu + mask, direct float4 stores ----
  if (lr < 12) {
#pragma unroll
    for (int jt = 0; jt < 2; ++jt) {
      int jl = jbase + jt * 16 + lg * 4;   // local j of r=0 (4-aligned)
      const float4 dv = jt ? dv1 : dv0;
      float4 st;
#pragma unroll
      for (int r = 0; r < 4; ++r) {
        float x = accB[jt][r] + be2v + srcv + (&dv.x)[r];
        x = (x > 0.0f) ? x : 0.01f * x;
        if (masks[jl + r] != 0.0f) x = -INFINITY;
        (&st.x)[r] = x;
      }
      *(float4*)(scores + ((((size_t)(b * SS + i)) * HH + lr) << 9) + j0c + jl) = st;
    }
  }
}

// ---------------------------------------------------------------------------
// Softmax over j (per b,i,h) + PV: gcnmid[b,i,:] = sum_j attn * feature[b,j,:]
// ---------------------------------------------------------------------------
__global__ __launch_bounds__(256) void k_softmax_pv(
    const float* __restrict__ scores, const float* __restrict__ feat,
    float* __restrict__ gout)
{
  __shared__ float p[2][12][512];
  int blk = blockIdx.x;
  int b = blk >> 8;
  int i0 = (blk & 255) << 1;
  int t = threadIdx.x;
  size_t base = ((size_t)(b * SS + i0) * HH) << 9;
  for (int q = t; q < 12288; q += 256) ((float*)p)[q] = scores[base + q];
  __syncthreads();

  int w = t >> 6, l = t & 63;
  for (int r = w; r < 24; r += 4) {
    int ii = r / 12, h = r % 12;
    float* row = p[ii][h];
    float vv[8];
    float m = -INFINITY;
#pragma unroll
    for (int u = 0; u < 8; ++u) {
      vv[u] = row[l + (u << 6)];
      m = fmaxf(m, vv[u]);
    }
#pragma unroll
    for (int o = 32; o > 0; o >>= 1) m = fmaxf(m, __shfl_xor(m, o));
    float s = 0.0f;
#pragma unroll
    for (int u = 0; u < 8; ++u) {
      float e = __expf(vv[u] - m);
      vv[u] = e;
      s += e;
    }
#pragma unroll
    for (int o = 32; o > 0; o >>= 1) s += __shfl_xor(s, o);
    float inv = 1.0f / s;
#pragma unroll
    for (int u = 0; u < 8; ++u) row[l + (u << 6)] = vv[u] * inv;
  }
  __syncthreads();

  float acc[2][3] = {};
  const float* fb = feat + (size_t)b * SS * DD;
  int h0 = t >> 6;
#pragma unroll 4
  for (int j = 0; j < 512; ++j) {
    const float* fr = fb + (size_t)j * DD;
    float f0 = fr[t], f1 = fr[t + 256], f2 = fr[t + 512];
    float p00 = p[0][h0][j], p10 = p[1][h0][j];
    float p01 = p[0][h0 + 4][j], p11 = p[1][h0 + 4][j];
    float p02 = p[0][h0 + 8][j], p12 = p[1][h0 + 8][j];
    acc[0][0] += p00 * f0; acc[0][1] += p01 * f1; acc[0][2] += p02 * f2;
    acc[1][0] += p10 * f0; acc[1][1] += p11 * f1; acc[1][2] += p12 * f2;
  }
#pragma unroll
  for (int ii = 0; ii < 2; ++ii)
#pragma unroll
    for (int u = 0; u < 3; ++u)
      gout[(size_t)(b * SS + i0 + ii) * DD + t + (u << 8)] = acc[ii][u];
}

// ---------------------------------------------------------------------------
// LayerNorm (torch variant: unbiased std, /(std+eps)) + ReLU -> node (d_out)
// ---------------------------------------------------------------------------
__global__ __launch_bounds__(256) void k_ln(
    const float* __restrict__ gcn2, const float* __restrict__ ga,
    const float* __restrict__ gb, float* __restrict__ out)
{
  __shared__ float rs[4], rss[4];
  int row = blockIdx.x;
  int t = threadIdx.x;
  const float* x = gcn2 + (size_t)row * DD;
  float v[3];
  float s = 0.0f, ss2 = 0.0f;
#pragma unroll
  for (int u = 0; u < 3; ++u) {
    v[u] = x[t + (u << 8)];
    s += v[u];
    ss2 += v[u] * v[u];
  }
#pragma unroll
  for (int o = 32; o > 0; o >>= 1) {
    s += __shfl_down(s, o);
    ss2 += __shfl_down(ss2, o);
  }
  int w = t >> 6, l = t & 63;
  if (l == 0) { rs[w] = s; rss[w] = ss2; }
  __syncthreads();
  float S = rs[0] + rs[1] + rs[2] + rs[3];
  float SSum = rss[0] + rss[1] + rss[2] + rss[3];
  float mean = S * (1.0f / 768.0f);
  float var = (SSum - 768.0f * mean * mean) * (1.0f / 767.0f);
  var = fmaxf(var, 0.0f);
  float rinv = 1.0f / (sqrtf(var) + 1e-6f);
#pragma unroll
  for (int u = 0; u < 3; ++u) {
    int cidx = t + (u << 8);
    float y = ga[cidx] * (v[u] - mean) * rinv + gb[cidx];
    out[(size_t)row * DD + cidx] = fmaxf(y, 0.0f);
  }
}

// ---------------------------------------------------------------------------
// P[b,s,f] = ediag[b,s]@Wh_ei^T + node[b,s]@Wh_n2^T
// Q[b,s,f] = ediag[b,s]@Wh_ej^T + node[b,s]@Wh_n1^T + bh
// 512 threads: (which, f, d-quadrant) per thread, shfl-reduce over quadrant.
// ---------------------------------------------------------------------------
__global__ __launch_bounds__(512) void k_pq(
    const float* __restrict__ node, const float* __restrict__ wadj,
    const float* __restrict__ Whei, const float* __restrict__ Whej,
    const float* __restrict__ Whn1, const float* __restrict__ Whn2,
    const float* __restrict__ bh, float* __restrict__ P, float* __restrict__ Q)
{
  __shared__ float nd[768];
  __shared__ float ed[50];
  int bs = blockIdx.x;
  int b = bs >> 9, s = bs & 511;
  int t = threadIdx.x;
  for (int q = t; q < 768; q += 512) nd[q] = node[(size_t)bs * DD + q];
  if (t < 50) ed[t] = wadj[((size_t)(b * SS + s) * SS + s) * EE + t];
  __syncthreads();
  int which = t >> 8;
  int r = t & 255;
  int f = r >> 2, dq = r & 3;
  if (f < 50) {
    const float* Wn = which ? Whn1 : Whn2;
    float acc = 0.0f;
    const float* wrow = Wn + f * DD + dq * 192;
    const float* ndp = nd + dq * 192;
#pragma unroll 4
    for (int d = 0; d < 192; ++d) acc += ndp[d] * wrow[d];
    if (dq == 0) {
      const float* We = which ? Whej : Whei;
      for (int e = 0; e < 50; ++e) acc += ed[e] * We[f * EE + e];
    }
    acc += __shfl_xor(acc, 1);
    acc += __shfl_xor(acc, 2);
    if (dq == 0) {
      float outv = acc + (which ? bh[f] : 0.0f);
      (which ? Q : P)[(size_t)bs * DE + f] = outv;
    }
  }
}

// ---------------------------------------------------------------------------
// edge_out[n,f] = wadj[n,:]@Wh_e[f,:] + P[b,i,f] + Q[b,j,f]
// Compute in regs, park tile in LDS (aliased over adjs), stream float4 out.
// ---------------------------------------------------------------------------
__global__ __launch_bounds__(256) void k_edge(
    const float* __restrict__ wadj, const float* __restrict__ Whe,
    const float* __restrict__ P, const float* __restrict__ Q,
    float* __restrict__ eout)
{
  __shared__ float adjs[128][51];
  __shared__ float whes[52][52];
  int t = threadIdx.x;
  size_t n0 = (size_t)blockIdx.x * 128;
  for (int q = t; q < 2500; q += 256) whes[q / 50][q % 50] = Whe[q];
  for (int q = t; q < 52 * 52 - 2600; q += 256) {
    int qq = q + 2600;
    whes[qq / 52][qq % 52] = 0.0f;
  }
  for (int q = t; q < 6400; q += 256) adjs[q / 50][q % 50] = wadj[n0 * EE + q];
  __syncthreads();

  int pl = t & 31;
  int fg = t >> 5;
  int f0 = fg < 2 ? fg * 7 : 14 + (fg - 2) * 6;
  int nf = fg < 2 ? 7 : 6;
  float acc[4][7] = {};
  for (int e = 0; e < 50; ++e) {
    float aw[7];
#pragma unroll
    for (int u = 0; u < 7; ++u) aw[u] = whes[f0 + u][e];
    float ap0 = adjs[pl][e], ap1 = adjs[pl + 32][e];
    float ap2 = adjs[pl + 64][e], ap3 = adjs[pl + 96][e];
#pragma unroll
    for (int u = 0; u < 7; ++u) {
      acc[0][u] += ap0 * aw[u];
      acc[1][u] += ap1 * aw[u];
      acc[2][u] += ap2 * aw[u];
      acc[3][u] += ap3 * aw[u];
    }
  }
  // finalize with P (block-row-uniform) and Q (per-j) in registers
  float fin[4][7];
#pragma unroll
  for (int pp = 0; pp < 4; ++pp) {
    size_t n = n0 + pl + 32 * pp;
    int b = (int)(n >> 18);
    int rem = (int)(n & 262143);
    int i = rem >> 9, j = rem & 511;
    const float* Pr = P + (size_t)(b * SS + i) * DE;
    const float* Qr = Q + (size_t)(b * SS + j) * DE;
    for (int u = 0; u < nf; ++u) {
      int f = f0 + u;
      fin[pp][u] = acc[pp][u] + Pr[f] + Qr[f];
    }
  }
  __syncthreads();  // everyone done reading adjs
  float* outs = &adjs[0][0];  // 6400-float tile, flat
#pragma unroll
  for (int pp = 0; pp < 4; ++pp)
    for (int u = 0; u < nf; ++u)
      outs[(pl + 32 * pp) * 50 + f0 + u] = fin[pp][u];
  __syncthreads();
  const float4* src4 = (const float4*)outs;
  float4* dst4 = (float4*)(eout + n0 * DE);
  for (int q = t; q < 1600; q += 256) dst4[q] = src4[q];
}

// ---------------------------------------------------------------------------
extern "C" void kernel_launch(void* const* d_in, const int* in_sizes, int n_in,
                              void* d_out, int out_size, void* d_ws, size_t ws_size,
                              hipStream_t stream)
{
  const float* wprob = (const float*)d_in[0];
  const float* wadj  = (const float*)d_in[1];
  const float* gin   = (const float*)d_in[2];
  const float* sloop = (const float*)d_in[3];
  const float* W_lin = (const float*)d_in[4];
  const float* b_lin = (const float*)d_in[5];
  const float* fw1   = (const float*)d_in[6];
  const float* fw2   = (const float*)d_in[7];
  const float* We1   = (const float*)d_in[8];
  const float* be1   = (const float*)d_in[9];
  const float* We2   = (const float*)d_in[10];
  const float* be2   = (const float*)d_in[11];
  const float* W_out = (const float*)d_in[12];
  const float* b_out = (const float*)d_in[13];
  const float* ln_a  = (const float*)d_in[14];
  const float* ln_b  = (const float*)d_in[15];
  const float* Whe   = (const float*)d_in[16];
  const float* Whei  = (const float*)d_in[17];
  const float* Whej  = (const float*)d_in[18];
  const float* Whn1  = (const float*)d_in[19];
  const float* Whn2  = (const float*)d_in[20];
  const float* bh    = (const float*)d_in[21];

  float* ws = (float*)d_ws;
  float* feature = ws + 0;         // [B,S,D]      786432
  float* src     = ws + 786432;    // [B,H,S]      12288
  float* dst     = ws + 798720;    // [B,H,S]      12288
  float* scores  = ws + 811008;    // [B,S,H,S]    6291456
  float* gcnmid  = ws + 7102464;   // [B,S,D]      786432
  float* gcn2    = ws + 7888896;   // [B,S,D]      786432
  float* P       = ws + 8675328;   // [B,S,DE]     51200
  float* Q       = ws + 8726528;   // [B,S,DE]     51200
  s16x8* wtab    = (s16x8*)(ws + 8777728);  // 20*64 s16x8 = 5120 floats
  float* betab   = ws + 8782848;   // 8*64 = 512 floats

  float* node = (float*)d_out;            // output 0: [B,S,D]
  float* eout = (float*)d_out + 786432;   // output 1: [B,S,S,DE]

  k_prep<<<1, 64, 0, stream>>>(We1, be1, We2, wtab, betab);
  k_gemm_bias<<<dim3(DD / 64, (BB * SS) / 64), 256, 0, stream>>>(
      gin, DD, W_lin, b_lin, feature, DD, BB * SS, DD, DD);
  k_attnvec<<<BB * SS, 192, 0, stream>>>(feature, fw1, fw2, src, dst);
  k_scores_mfma<<<BB * SS * 4, 256, 0, stream>>>(
      wprob, sloop, wtab, betab, be2, src, dst, scores);
  k_softmax_pv<<<BB * SS / 2, 256, 0, stream>>>(scores, feature, gcnmid);
  k_gemm_bias<<<dim3(DD / 64, (BB * SS) / 64), 256, 0, stream>>>(
      gcnmid, DD, W_out, b_out, gcn2, DD, BB * SS, DD, DD);
  k_ln<<<BB * SS, 256, 0, stream>>>(gcn2, ln_a, ln_b, node);
  k_pq<<<BB * SS, 512, 0, stream>>>(node, wadj, Whei, Whej, Whn1, Whn2, bh, P, Q);
  k_edge<<<(BB * SS * SS) / 128, 256, 0, stream>>>(wadj, Whe, P, Q, eout);
}

// Round 6
// 364.948 us; speedup vs baseline: 1.6723x; 1.0806x over previous
//
#include <hip/hip_runtime.h>
#include <math.h>
#include <stddef.h>

// Problem constants
#define BB 2
#define SS 512
#define DD 768
#define HH 12
#define HDIM 64
#define EE 50
#define DE 50
#define F1 128

typedef float f32x4 __attribute__((ext_vector_type(4)));
typedef short s16x8 __attribute__((ext_vector_type(8)));

// f32 -> bf16 bits, round-to-nearest-even
static __device__ __forceinline__ unsigned short f2bf(float x) {
  unsigned int u = __float_as_uint(x);
  unsigned int r = u + 0x7fffu + ((u >> 16) & 1u);
  return (unsigned short)(r >> 16);
}
static __device__ __forceinline__ float bf2f(unsigned short b) {
  return __uint_as_float(((unsigned int)b) << 16);
}

// ---------------------------------------------------------------------------
// Generic tiled f32 GEMM: Y[m][n] = sum_k X[m][k] * W[n][k] + bias[n]
// ---------------------------------------------------------------------------
__global__ __launch_bounds__(256) void k_gemm_bias(
    const float* __restrict__ X, int ldx,
    const float* __restrict__ W,   // [N][K] row-major
    const float* __restrict__ bias,
    float* __restrict__ Y, int ldy,
    int M, int N, int K)
{
  __shared__ float Xs[32][68];
  __shared__ float Ws[32][68];
  int t = threadIdx.x;
  int tx = t & 15, ty = t >> 4;
  int m0 = blockIdx.y * 64, n0 = blockIdx.x * 64;
  float acc[4][4] = {};
  for (int k0 = 0; k0 < K; k0 += 32) {
#pragma unroll
    for (int q = 0; q < 2; ++q) {
      int idx = t + q * 256;
      int r = idx >> 3, c = (idx & 7) << 2;
      float4 v = *(const float4*)(X + (size_t)(m0 + r) * ldx + k0 + c);
      Xs[c + 0][r] = v.x; Xs[c + 1][r] = v.y; Xs[c + 2][r] = v.z; Xs[c + 3][r] = v.w;
      float4 w = *(const float4*)(W + (size_t)(n0 + r) * K + k0 + c);
      Ws[c + 0][r] = w.x; Ws[c + 1][r] = w.y; Ws[c + 2][r] = w.z; Ws[c + 3][r] = w.w;
    }
    __syncthreads();
#pragma unroll
    for (int kk = 0; kk < 32; ++kk) {
      float a[4], b[4];
#pragma unroll
      for (int u = 0; u < 4; ++u) a[u] = Xs[kk][ty * 4 + u];
#pragma unroll
      for (int u = 0; u < 4; ++u) b[u] = Ws[kk][tx * 4 + u];
#pragma unroll
      for (int i = 0; i < 4; ++i)
#pragma unroll
        for (int j = 0; j < 4; ++j) acc[i][j] += a[i] * b[j];
    }
    __syncthreads();
  }
#pragma unroll
  for (int i = 0; i < 4; ++i) {
    int m = m0 + ty * 4 + i;
#pragma unroll
    for (int j = 0; j < 4; ++j) {
      int n = n0 + tx * 4 + j;
      Y[(size_t)m * ldy + n] = acc[i][j] + bias[n];
    }
  }
}

// ---------------------------------------------------------------------------
// attn_src[b,h,s], attn_dst[b,h,s]
// ---------------------------------------------------------------------------
__global__ __launch_bounds__(192) void k_attnvec(
    const float* __restrict__ feat, const float* __restrict__ w1,
    const float* __restrict__ w2, float* __restrict__ src, float* __restrict__ dst)
{
  int bs = blockIdx.x;
  int t = threadIdx.x;
  int h = t >> 4, l = t & 15;
  float4 f = *(const float4*)(feat + (size_t)bs * DD + h * HDIM + l * 4);
  float4 a = *(const float4*)(w1 + h * HDIM + l * 4);
  float4 c = *(const float4*)(w2 + h * HDIM + l * 4);
  float ps = f.x * a.x + f.y * a.y + f.z * a.z + f.w * a.w;
  float pd = f.x * c.x + f.y * c.y + f.z * c.z + f.w * c.w;
#pragma unroll
  for (int o = 8; o > 0; o >>= 1) {
    ps += __shfl_xor(ps, o);
    pd += __shfl_xor(pd, o);
  }
  if (l == 0) {
    int b = bs >> 9, s = bs & 511;
    src[((b * HH + h) << 9) + s] = ps;
    dst[((b * HH + h) << 9) + s] = pd;
  }
}

// ---------------------------------------------------------------------------
// Precompute per-lane MFMA weight fragments (lane-only dependent, 64 variants)
// wtab[k][lane] : s16x8;  k = ks*8+n (We1 frags, 0..15), 16+kk (We2, 16..19)
// betab[n][lane]: f32     be1[n*16 + (lane&15)]
// wtabE[nt*2+ks][lane]: Whe B-frags for the edge GEMM (f=nt*16+lr, e=ks*32+..)
// ---------------------------------------------------------------------------
__global__ __launch_bounds__(64) void k_prep(
    const float* __restrict__ We1, const float* __restrict__ be1,
    const float* __restrict__ We2, const float* __restrict__ Whe,
    s16x8* __restrict__ wtab, float* __restrict__ betab,
    s16x8* __restrict__ wtabE)
{
  const int l = threadIdx.x;
  const int lr = l & 15, lg = l >> 4;
#pragma unroll
  for (int ks = 0; ks < 2; ++ks)
#pragma unroll
    for (int n = 0; n < 8; ++n) {
      s16x8 v;
#pragma unroll
      for (int u = 0; u < 8; ++u) {
        int e = ks * 32 + lg * 8 + u;
        float x = (e < 50) ? We1[(n * 16 + lr) * 50 + e] : 0.0f;
        v[u] = (short)f2bf(x);
      }
      wtab[(ks * 8 + n) * 64 + l] = v;
    }
#pragma unroll
  for (int kk = 0; kk < 4; ++kk) {
    s16x8 v;
#pragma unroll
    for (int u = 0; u < 8; ++u) {
      int f = kk * 32 + lg * 8 + u;
      v[u] = (short)((lr < 12) ? f2bf(We2[lr * 128 + f]) : (unsigned short)0);
    }
    wtab[(16 + kk) * 64 + l] = v;
  }
#pragma unroll
  for (int n = 0; n < 8; ++n) betab[n * 64 + l] = be1[n * 16 + lr];
#pragma unroll
  for (int nt = 0; nt < 4; ++nt)
#pragma unroll
    for (int ks = 0; ks < 2; ++ks) {
      int f = nt * 16 + lr;
      s16x8 v;
#pragma unroll
      for (int u = 0; u < 8; ++u) {
        int e = ks * 32 + lg * 8 + u;
        float x = (f < 50 && e < 50) ? Whe[f * 50 + e] : 0.0f;
        v[u] = (short)f2bf(x);
      }
      wtabE[(nt * 2 + ks) * 64 + l] = v;
    }
}

// ---------------------------------------------------------------------------
// MFMA fused edge-MLP -> attention scores. One block per (b, i, j-chunk of
// 128): 4096 independent blocks, 3 blocks/CU. Weight fragments come from the
// precomputed lane table (20 coalesced 16B loads, L2-resident).
// 256 threads = 4 waves; wave w owns j-rows [w*32, w*32+32).
// scores layout: [b][i][h][j]
// ---------------------------------------------------------------------------
__global__ __launch_bounds__(256, 3) void k_scores_mfma(
    const float* __restrict__ wprob, const float* __restrict__ sloop,
    const s16x8* __restrict__ wtab, const float* __restrict__ betab,
    const float* __restrict__ be2,
    const float* __restrict__ src, const float* __restrict__ dst,
    float* __restrict__ scores)
{
  __shared__ unsigned short wps_s[128][72];    // [j][e] bf16, 18.4 KB
  __shared__ unsigned short hmid_s[128][132];  // [j][f] bf16, 33.8 KB
  __shared__ float masks[128];

  const int blk = blockIdx.x;        // (b*512 + i)*4 + c
  const int c = blk & 3;
  const int i = (blk >> 2) & 511;
  const int b = blk >> 11;
  const int j0c = c << 7;
  const int t = threadIdx.x;
  const int w = t >> 6, l = t & 63;
  const int lr = l & 15, lg = l >> 4;
  const int jbase = w * 32;

  // ---- issue the HBM loads for this chunk FIRST (28 float4/thread) ----
  const size_t rowbase = (size_t)(b * SS + i) * SS * EE + (size_t)c * 6400;
  float4 pw[7], psl[7];
  {
    const float* wp = wprob + rowbase;
    const float* sl = sloop + rowbase;
#pragma unroll
    for (int k = 0; k < 7; ++k)
      if (k < 6 || t < 64) {
        pw[k] = *(const float4*)(wp + 4 * (t + 256 * k));
        psl[k] = *(const float4*)(sl + 4 * (t + 256 * k));
      }
  }

  // ---- weight fragments from lane table (coalesced, L2-resident) ----
  s16x8 wa[2][8];
#pragma unroll
  for (int ks = 0; ks < 2; ++ks)
#pragma unroll
    for (int n = 0; n < 8; ++n) wa[ks][n] = wtab[(ks * 8 + n) * 64 + l];
  s16x8 wb[4];
#pragma unroll
  for (int kk = 0; kk < 4; ++kk) wb[kk] = wtab[(16 + kk) * 64 + l];
  float be1v[8];
#pragma unroll
  for (int n = 0; n < 8; ++n) be1v[n] = betab[n * 64 + l];
  const int hc = (lr < 12) ? lr : 0;
  const float be2v = be2[hc];
  const float srcv = src[((b * HH + hc) << 9) + i];
  const float* drow = dst + ((size_t)(b * HH + hc) << 9);
  float4 dv0 = *(const float4*)(drow + j0c + jbase + lg * 4);
  float4 dv1 = *(const float4*)(drow + j0c + jbase + 16 + lg * 4);

  // zero pad cols e=50..63 (dwords 25..31 of each 36-dword row)
  for (int q = t; q < 896; q += 256) {
    int r = q / 7, cd = 25 + q % 7;
    ((unsigned int*)wps_s)[r * 36 + cd] = 0u;
  }

  // ---- LDS write (waits on wps loads) ----
#pragma unroll
  for (int k = 0; k < 7; ++k)
    if (k < 6 || t < 64) {
      int f = 4 * (t + 256 * k);
      int j = f / 50;
      int e0 = f - j * 50;
      float vs[4] = {pw[k].x + psl[k].x, pw[k].y + psl[k].y,
                     pw[k].z + psl[k].z, pw[k].w + psl[k].w};
#pragma unroll
      for (int u = 0; u < 4; ++u) {
        int e = e0 + u, jj = j;
        if (e >= 50) { e -= 50; jj += 1; }
        wps_s[jj][e] = f2bf(vs[u]);
      }
    }
  __syncthreads();

  // per-wave masks for own j-rows (wave-local write+read; no extra barrier)
  if (l < 32) {
    const unsigned short* row = wps_s[jbase + l];
    float s = 0.0f;
#pragma unroll
    for (int q = 0; q < 6; ++q) {
      s16x8 v = *(const s16x8*)(row + q * 8);
#pragma unroll
      for (int u = 0; u < 8; ++u) s += bf2f((unsigned short)v[u]);
    }
    unsigned int last = *(const unsigned int*)(row + 48);
    s += bf2f((unsigned short)(last & 0xffffu)) + bf2f((unsigned short)(last >> 16));
    masks[jbase + l] = (s == 0.0f) ? 1.0f : 0.0f;
  }

  // ---- stage A: hmid = relu(wps @ We1^T + be1) ----
  f32x4 accA[2][8] = {};
#pragma unroll
  for (int ks = 0; ks < 2; ++ks) {
    s16x8 a0 = *(const s16x8*)&wps_s[jbase + lr][ks * 32 + lg * 8];
    s16x8 a1 = *(const s16x8*)&wps_s[jbase + 16 + lr][ks * 32 + lg * 8];
#pragma unroll
    for (int n = 0; n < 8; ++n) {
      accA[0][n] = __builtin_amdgcn_mfma_f32_16x16x32_bf16(a0, wa[ks][n], accA[0][n], 0, 0, 0);
      accA[1][n] = __builtin_amdgcn_mfma_f32_16x16x32_bf16(a1, wa[ks][n], accA[1][n], 0, 0, 0);
    }
  }
#pragma unroll
  for (int jt = 0; jt < 2; ++jt)
#pragma unroll
    for (int n = 0; n < 8; ++n)
#pragma unroll
      for (int r = 0; r < 4; ++r) {
        float v = fmaxf(accA[jt][n][r] + be1v[n], 0.0f);
        hmid_s[jbase + jt * 16 + lg * 4 + r][n * 16 + lr] = f2bf(v);
      }

  // ---- stage B: A = hmid @ We2^T (wave-local rows; no barrier) ----
  f32x4 accB[2] = {};
#pragma unroll
  for (int kk = 0; kk < 4; ++kk) {
    s16x8 a0 = *(const s16x8*)&hmid_s[jbase + lr][kk * 32 + lg * 8];
    s16x8 a1 = *(const s16x8*)&hmid_s[jbase + 16 + lr][kk * 32 + lg * 8];
    accB[0] = __builtin_amdgcn_mfma_f32_16x16x32_bf16(a0, wb[kk], accB[0], 0, 0, 0);
    accB[1] = __builtin_amdgcn_mfma_f32_16x16x32_bf16(a1, wb[kk], accB[1], 0, 0, 0);
  }

  // ---- epilogue: leaky-relu + mask, direct float4 stores ----
  if (lr < 12) {
#pragma unroll
    for (int jt = 0; jt < 2; ++jt) {
      int jl = jbase + jt * 16 + lg * 4;   // local j of r=0 (4-aligned)
      const float4 dv = jt ? dv1 : dv0;
      float4 st;
#pragma unroll
      for (int r = 0; r < 4; ++r) {
        float x = accB[jt][r] + be2v + srcv + (&dv.x)[r];
        x = (x > 0.0f) ? x : 0.01f * x;
        if (masks[jl + r] != 0.0f) x = -INFINITY;
        (&st.x)[r] = x;
      }
      *(float4*)(scores + ((((size_t)(b * SS + i)) * HH + lr) << 9) + j0c + jl) = st;
    }
  }
}

// ---------------------------------------------------------------------------
// Softmax over j (per b,i,h) + PV: gcnmid[b,i,:] = sum_j attn * feature[b,j,:]
// ---------------------------------------------------------------------------
__global__ __launch_bounds__(256) void k_softmax_pv(
    const float* __restrict__ scores, const float* __restrict__ feat,
    float* __restrict__ gout)
{
  __shared__ float p[2][12][512];
  int blk = blockIdx.x;
  int b = blk >> 8;
  int i0 = (blk & 255) << 1;
  int t = threadIdx.x;
  size_t base = ((size_t)(b * SS + i0) * HH) << 9;
  for (int q = t; q < 12288; q += 256) ((float*)p)[q] = scores[base + q];
  __syncthreads();

  int w = t >> 6, l = t & 63;
  for (int r = w; r < 24; r += 4) {
    int ii = r / 12, h = r % 12;
    float* row = p[ii][h];
    float vv[8];
    float m = -INFINITY;
#pragma unroll
    for (int u = 0; u < 8; ++u) {
      vv[u] = row[l + (u << 6)];
      m = fmaxf(m, vv[u]);
    }
#pragma unroll
    for (int o = 32; o > 0; o >>= 1) m = fmaxf(m, __shfl_xor(m, o));
    float s = 0.0f;
#pragma unroll
    for (int u = 0; u < 8; ++u) {
      float e = __expf(vv[u] - m);
      vv[u] = e;
      s += e;
    }
#pragma unroll
    for (int o = 32; o > 0; o >>= 1) s += __shfl_xor(s, o);
    float inv = 1.0f / s;
#pragma unroll
    for (int u = 0; u < 8; ++u) row[l + (u << 6)] = vv[u] * inv;
  }
  __syncthreads();

  float acc[2][3] = {};
  const float* fb = feat + (size_t)b * SS * DD;
  int h0 = t >> 6;
#pragma unroll 4
  for (int j = 0; j < 512; ++j) {
    const float* fr = fb + (size_t)j * DD;
    float f0 = fr[t], f1 = fr[t + 256], f2 = fr[t + 512];
    float p00 = p[0][h0][j], p10 = p[1][h0][j];
    float p01 = p[0][h0 + 4][j], p11 = p[1][h0 + 4][j];
    float p02 = p[0][h0 + 8][j], p12 = p[1][h0 + 8][j];
    acc[0][0] += p00 * f0; acc[0][1] += p01 * f1; acc[0][2] += p02 * f2;
    acc[1][0] += p10 * f0; acc[1][1] += p11 * f1; acc[1][2] += p12 * f2;
  }
#pragma unroll
  for (int ii = 0; ii < 2; ++ii)
#pragma unroll
    for (int u = 0; u < 3; ++u)
      gout[(size_t)(b * SS + i0 + ii) * DD + t + (u << 8)] = acc[ii][u];
}

// ---------------------------------------------------------------------------
// LayerNorm (torch variant: unbiased std, /(std+eps)) + ReLU -> node (d_out)
// ---------------------------------------------------------------------------
__global__ __launch_bounds__(256) void k_ln(
    const float* __restrict__ gcn2, const float* __restrict__ ga,
    const float* __restrict__ gb, float* __restrict__ out)
{
  __shared__ float rs[4], rss[4];
  int row = blockIdx.x;
  int t = threadIdx.x;
  const float* x = gcn2 + (size_t)row * DD;
  float v[3];
  float s = 0.0f, ss2 = 0.0f;
#pragma unroll
  for (int u = 0; u < 3; ++u) {
    v[u] = x[t + (u << 8)];
    s += v[u];
    ss2 += v[u] * v[u];
  }
#pragma unroll
  for (int o = 32; o > 0; o >>= 1) {
    s += __shfl_down(s, o);
    ss2 += __shfl_down(ss2, o);
  }
  int w = t >> 6, l = t & 63;
  if (l == 0) { rs[w] = s; rss[w] = ss2; }
  __syncthreads();
  float S = rs[0] + rs[1] + rs[2] + rs[3];
  float SSum = rss[0] + rss[1] + rss[2] + rss[3];
  float mean = S * (1.0f / 768.0f);
  float var = (SSum - 768.0f * mean * mean) * (1.0f / 767.0f);
  var = fmaxf(var, 0.0f);
  float rinv = 1.0f / (sqrtf(var) + 1e-6f);
#pragma unroll
  for (int u = 0; u < 3; ++u) {
    int cidx = t + (u << 8);
    float y = ga[cidx] * (v[u] - mean) * rinv + gb[cidx];
    out[(size_t)row * DD + cidx] = fmaxf(y, 0.0f);
  }
}

// ---------------------------------------------------------------------------
// P[b,s,f] = ediag[b,s]@Wh_ei^T + node[b,s]@Wh_n2^T
// Q[b,s,f] = ediag[b,s]@Wh_ej^T + node[b,s]@Wh_n1^T + bh
// 512 threads: (which, f, d-quadrant) per thread, shfl-reduce over quadrant.
// ---------------------------------------------------------------------------
__global__ __launch_bounds__(512) void k_pq(
    const float* __restrict__ node, const float* __restrict__ wadj,
    const float* __restrict__ Whei, const float* __restrict__ Whej,
    const float* __restrict__ Whn1, const float* __restrict__ Whn2,
    const float* __restrict__ bh, float* __restrict__ P, float* __restrict__ Q)
{
  __shared__ float nd[768];
  __shared__ float ed[50];
  int bs = blockIdx.x;
  int b = bs >> 9, s = bs & 511;
  int t = threadIdx.x;
  for (int q = t; q < 768; q += 512) nd[q] = node[(size_t)bs * DD + q];
  if (t < 50) ed[t] = wadj[((size_t)(b * SS + s) * SS + s) * EE + t];
  __syncthreads();
  int which = t >> 8;
  int r = t & 255;
  int f = r >> 2, dq = r & 3;
  if (f < 50) {
    const float* Wn = which ? Whn1 : Whn2;
    float acc = 0.0f;
    const float* wrow = Wn + f * DD + dq * 192;
    const float* ndp = nd + dq * 192;
#pragma unroll 4
    for (int d = 0; d < 192; ++d) acc += ndp[d] * wrow[d];
    if (dq == 0) {
      const float* We = which ? Whej : Whei;
      for (int e = 0; e < 50; ++e) acc += ed[e] * We[f * EE + e];
    }
    acc += __shfl_xor(acc, 1);
    acc += __shfl_xor(acc, 2);
    if (dq == 0) {
      float outv = acc + (which ? bh[f] : 0.0f);
      (which ? Q : P)[(size_t)bs * DE + f] = outv;
    }
  }
}

// ---------------------------------------------------------------------------
// MFMA edge refine: edge_out[n,f] = wadj[n,:]@Whe[f,:] + P[b,i,f] + Q[b,j,f]
// One block per 128 consecutive pairs (same i, contiguous j). 256 thr = 4
// waves; wave w owns pair-rows [w*32, w*32+32) (2 M-tiles). N=64 (50 valid),
// K=64 (50 valid). Whe B-frags from lane table; epilogue adds P (LDS,
// block-uniform) + Q (L2-resident) and stores scalar f32 (16-lane contig).
// ---------------------------------------------------------------------------
__global__ __launch_bounds__(256) void k_edge_mfma(
    const float* __restrict__ wadj, const s16x8* __restrict__ wtabE,
    const float* __restrict__ P, const float* __restrict__ Q,
    float* __restrict__ eout)
{
  __shared__ unsigned short adj_s[128][72];   // [pair][e] bf16, 18.4 KB
  __shared__ float P_s[64];

  const int t = threadIdx.x;
  const size_t n0 = (size_t)blockIdx.x * 128;
  const int b = (int)(n0 >> 18);
  const int i = (int)((n0 & 262143) >> 9);
  const int j0 = (int)(n0 & 511);
  const int w = t >> 6, l = t & 63;
  const int lr = l & 15, lg = l >> 4;
  const int mbase = w * 32;

  // ---- issue wadj tile loads first (7 float4/thread for 6400 floats) ----
  float4 pw[7];
  {
    const float* wp = wadj + n0 * EE;
#pragma unroll
    for (int k = 0; k < 7; ++k)
      if (k < 6 || t < 64) pw[k] = *(const float4*)(wp + 4 * (t + 256 * k));
  }

  // ---- B-fragments from lane table; P row to LDS ----
  s16x8 we[4][2];
#pragma unroll
  for (int nt = 0; nt < 4; ++nt)
#pragma unroll
    for (int ks = 0; ks < 2; ++ks) we[nt][ks] = wtabE[(nt * 2 + ks) * 64 + l];
  if (t < 64) P_s[t] = (t < 50) ? P[(size_t)(b * SS + i) * DE + t] : 0.0f;

  // zero pad cols e=50..63 (dwords 25..31 of each 36-dword row)
  for (int q = t; q < 896; q += 256) {
    int r = q / 7, cd = 25 + q % 7;
    ((unsigned int*)adj_s)[r * 36 + cd] = 0u;
  }

  // ---- LDS write (waits on wadj loads) ----
#pragma unroll
  for (int k = 0; k < 7; ++k)
    if (k < 6 || t < 64) {
      int f = 4 * (t + 256 * k);
      int j = f / 50;
      int e0 = f - j * 50;
#pragma unroll
      for (int u = 0; u < 4; ++u) {
        int e = e0 + u, jj = j;
        if (e >= 50) { e -= 50; jj += 1; }
        adj_s[jj][e] = f2bf((&pw[k].x)[u]);
      }
    }
  __syncthreads();

  // ---- MFMA: [128 x 64(e)] @ [64(e) x 64(f)] ----
  f32x4 acc[2][4] = {};
#pragma unroll
  for (int ks = 0; ks < 2; ++ks) {
    s16x8 a0 = *(const s16x8*)&adj_s[mbase + lr][ks * 32 + lg * 8];
    s16x8 a1 = *(const s16x8*)&adj_s[mbase + 16 + lr][ks * 32 + lg * 8];
#pragma unroll
    for (int nt = 0; nt < 4; ++nt) {
      acc[0][nt] = __builtin_amdgcn_mfma_f32_16x16x32_bf16(a0, we[nt][ks], acc[0][nt], 0, 0, 0);
      acc[1][nt] = __builtin_amdgcn_mfma_f32_16x16x32_bf16(a1, we[nt][ks], acc[1][nt], 0, 0, 0);
    }
  }

  // ---- epilogue: + P[i][f] + Q[j][f], scalar stores (16-lane contiguous) ----
#pragma unroll
  for (int nt = 0; nt < 4; ++nt) {
    int f = nt * 16 + lr;
    if (f < 50) {
      float pf = P_s[f];
#pragma unroll
      for (int mt = 0; mt < 2; ++mt) {
        int m = mbase + mt * 16 + lg * 4;
        const float* qp = Q + (size_t)(b * SS + j0 + m) * DE + f;
        float* op = eout + (n0 + m) * DE + f;
#pragma unroll
        for (int r = 0; r < 4; ++r)
          op[r * DE] = acc[mt][nt][r] + pf + qp[r * DE];
      }
    }
  }
}

// ---------------------------------------------------------------------------
extern "C" void kernel_launch(void* const* d_in, const int* in_sizes, int n_in,
                              void* d_out, int out_size, void* d_ws, size_t ws_size,
                              hipStream_t stream)
{
  const float* wprob = (const float*)d_in[0];
  const float* wadj  = (const float*)d_in[1];
  const float* gin   = (const float*)d_in[2];
  const float* sloop = (const float*)d_in[3];
  const float* W_lin = (const float*)d_in[4];
  const float* b_lin = (const float*)d_in[5];
  const float* fw1   = (const float*)d_in[6];
  const float* fw2   = (const float*)d_in[7];
  const float* We1   = (const float*)d_in[8];
  const float* be1   = (const float*)d_in[9];
  const float* We2   = (const float*)d_in[10];
  const float* be2   = (const float*)d_in[11];
  const float* W_out = (const float*)d_in[12];
  const float* b_out = (const float*)d_in[13];
  const float* ln_a  = (const float*)d_in[14];
  const float* ln_b  = (const float*)d_in[15];
  const float* Whe   = (const float*)d_in[16];
  const float* Whei  = (const float*)d_in[17];
  const float* Whej  = (const float*)d_in[18];
  const float* Whn1  = (const float*)d_in[19];
  const float* Whn2  = (const float*)d_in[20];
  const float* bh    = (const float*)d_in[21];

  float* ws = (float*)d_ws;
  float* feature = ws + 0;         // [B,S,D]      786432
  float* src     = ws + 786432;    // [B,H,S]      12288
  float* dst     = ws + 798720;    // [B,H,S]      12288
  float* scores  = ws + 811008;    // [B,S,H,S]    6291456
  float* gcnmid  = ws + 7102464;   // [B,S,D]      786432
  float* gcn2    = ws + 7888896;   // [B,S,D]      786432
  float* P       = ws + 8675328;   // [B,S,DE]     51200
  float* Q       = ws + 8726528;   // [B,S,DE]     51200
  s16x8* wtab    = (s16x8*)(ws + 8777728);  // 20*64 frags = 5120 floats
  float* betab   = ws + 8782848;   // 8*64 = 512 floats
  s16x8* wtabE   = (s16x8*)(ws + 8783360);  // 8*64 frags = 2048 floats

  float* node = (float*)d_out;            // output 0: [B,S,D]
  float* eout = (float*)d_out + 786432;   // output 1: [B,S,S,DE]

  k_prep<<<1, 64, 0, stream>>>(We1, be1, We2, Whe, wtab, betab, wtabE);
  k_gemm_bias<<<dim3(DD / 64, (BB * SS) / 64), 256, 0, stream>>>(
      gin, DD, W_lin, b_lin, feature, DD, BB * SS, DD, DD);
  k_attnvec<<<BB * SS, 192, 0, stream>>>(feature, fw1, fw2, src, dst);
  k_scores_mfma<<<BB * SS * 4, 256, 0, stream>>>(
      wprob, sloop, wtab, betab, be2, src, dst, scores);
  k_softmax_pv<<<BB * SS / 2, 256, 0, stream>>>(scores, feature, gcnmid);
  k_gemm_bias<<<dim3(DD / 64, (BB * SS) / 64), 256, 0, stream>>>(
      gcnmid, DD, W_out, b_out, gcn2, DD, BB * SS, DD, DD);
  k_ln<<<BB * SS, 256, 0, stream>>>(gcn2, ln_a, ln_b, node);
  k_pq<<<BB * SS, 512, 0, stream>>>(node, wadj, Whei, Whej, Whn1, Whn2, bh, P, Q);
  k_edge_mfma<<<(BB * SS * SS) / 128, 256, 0, stream>>>(wadj, wtabE, P, Q, eout);
}

// Round 8
// 302.170 us; speedup vs baseline: 2.0198x; 1.2078x over previous
//
#include <hip/hip_runtime.h>
#include <math.h>
#include <stddef.h>

// Problem constants
#define BB 2
#define SS 512
#define DD 768
#define HH 12
#define HDIM 64
#define EE 50
#define DE 50
#define F1 128

typedef float f32x4 __attribute__((ext_vector_type(4)));
typedef short s16x8 __attribute__((ext_vector_type(8)));

// f32 -> bf16 bits, round-to-nearest-even
static __device__ __forceinline__ unsigned short f2bf(float x) {
  unsigned int u = __float_as_uint(x);
  unsigned int r = u + 0x7fffu + ((u >> 16) & 1u);
  return (unsigned short)(r >> 16);
}
static __device__ __forceinline__ float bf2f(unsigned short b) {
  return __uint_as_float(((unsigned int)b) << 16);
}

// ---------------------------------------------------------------------------
// Generic tiled f32 GEMM: Y[m][n] = sum_k X[m][k] * W[n][k] + bias[n]
// ---------------------------------------------------------------------------
__global__ __launch_bounds__(256) void k_gemm_bias(
    const float* __restrict__ X, int ldx,
    const float* __restrict__ W,   // [N][K] row-major
    const float* __restrict__ bias,
    float* __restrict__ Y, int ldy,
    int M, int N, int K)
{
  __shared__ float Xs[32][68];
  __shared__ float Ws[32][68];
  int t = threadIdx.x;
  int tx = t & 15, ty = t >> 4;
  int m0 = blockIdx.y * 64, n0 = blockIdx.x * 64;
  float acc[4][4] = {};
  for (int k0 = 0; k0 < K; k0 += 32) {
#pragma unroll
    for (int q = 0; q < 2; ++q) {
      int idx = t + q * 256;
      int r = idx >> 3, c = (idx & 7) << 2;
      float4 v = *(const float4*)(X + (size_t)(m0 + r) * ldx + k0 + c);
      Xs[c + 0][r] = v.x; Xs[c + 1][r] = v.y; Xs[c + 2][r] = v.z; Xs[c + 3][r] = v.w;
      float4 w = *(const float4*)(W + (size_t)(n0 + r) * K + k0 + c);
      Ws[c + 0][r] = w.x; Ws[c + 1][r] = w.y; Ws[c + 2][r] = w.z; Ws[c + 3][r] = w.w;
    }
    __syncthreads();
#pragma unroll
    for (int kk = 0; kk < 32; ++kk) {
      float a[4], b[4];
#pragma unroll
      for (int u = 0; u < 4; ++u) a[u] = Xs[kk][ty * 4 + u];
#pragma unroll
      for (int u = 0; u < 4; ++u) b[u] = Ws[kk][tx * 4 + u];
#pragma unroll
      for (int i = 0; i < 4; ++i)
#pragma unroll
        for (int j = 0; j < 4; ++j) acc[i][j] += a[i] * b[j];
    }
    __syncthreads();
  }
#pragma unroll
  for (int i = 0; i < 4; ++i) {
    int m = m0 + ty * 4 + i;
#pragma unroll
    for (int j = 0; j < 4; ++j) {
      int n = n0 + tx * 4 + j;
      Y[(size_t)m * ldy + n] = acc[i][j] + bias[n];
    }
  }
}

// ---------------------------------------------------------------------------
// attn_src[b,h,s], attn_dst[b,h,s]
// ---------------------------------------------------------------------------
__global__ __launch_bounds__(192) void k_attnvec(
    const float* __restrict__ feat, const float* __restrict__ w1,
    const float* __restrict__ w2, float* __restrict__ src, float* __restrict__ dst)
{
  int bs = blockIdx.x;
  int t = threadIdx.x;
  int h = t >> 4, l = t & 15;
  float4 f = *(const float4*)(feat + (size_t)bs * DD + h * HDIM + l * 4);
  float4 a = *(const float4*)(w1 + h * HDIM + l * 4);
  float4 c = *(const float4*)(w2 + h * HDIM + l * 4);
  float ps = f.x * a.x + f.y * a.y + f.z * a.z + f.w * a.w;
  float pd = f.x * c.x + f.y * c.y + f.z * c.z + f.w * c.w;
#pragma unroll
  for (int o = 8; o > 0; o >>= 1) {
    ps += __shfl_xor(ps, o);
    pd += __shfl_xor(pd, o);
  }
  if (l == 0) {
    int b = bs >> 9, s = bs & 511;
    src[((b * HH + h) << 9) + s] = ps;
    dst[((b * HH + h) << 9) + s] = pd;
  }
}

// ---------------------------------------------------------------------------
// Precompute per-lane MFMA weight fragments (lane-only dependent, 64 variants)
// wtab[k][lane] : s16x8;  k = ks*8+n (We1 frags, 0..15), 16+kk (We2, 16..19)
// betab[n][lane]: f32     be1[n*16 + (lane&15)]
// wtabE[nt*2+ks][lane]: Whe B-frags for the edge GEMM (f=nt*16+lr, e=ks*32+..)
// ---------------------------------------------------------------------------
__global__ __launch_bounds__(64) void k_prep(
    const float* __restrict__ We1, const float* __restrict__ be1,
    const float* __restrict__ We2, const float* __restrict__ Whe,
    s16x8* __restrict__ wtab, float* __restrict__ betab,
    s16x8* __restrict__ wtabE)
{
  const int l = threadIdx.x;
  const int lr = l & 15, lg = l >> 4;
#pragma unroll
  for (int ks = 0; ks < 2; ++ks)
#pragma unroll
    for (int n = 0; n < 8; ++n) {
      s16x8 v;
#pragma unroll
      for (int u = 0; u < 8; ++u) {
        int e = ks * 32 + lg * 8 + u;
        float x = (e < 50) ? We1[(n * 16 + lr) * 50 + e] : 0.0f;
        v[u] = (short)f2bf(x);
      }
      wtab[(ks * 8 + n) * 64 + l] = v;
    }
#pragma unroll
  for (int kk = 0; kk < 4; ++kk) {
    s16x8 v;
#pragma unroll
    for (int u = 0; u < 8; ++u) {
      int f = kk * 32 + lg * 8 + u;
      v[u] = (short)((lr < 12) ? f2bf(We2[lr * 128 + f]) : (unsigned short)0);
    }
    wtab[(16 + kk) * 64 + l] = v;
  }
#pragma unroll
  for (int n = 0; n < 8; ++n) betab[n * 64 + l] = be1[n * 16 + lr];
#pragma unroll
  for (int nt = 0; nt < 4; ++nt)
#pragma unroll
    for (int ks = 0; ks < 2; ++ks) {
      int f = nt * 16 + lr;
      s16x8 v;
#pragma unroll
      for (int u = 0; u < 8; ++u) {
        int e = ks * 32 + lg * 8 + u;
        float x = (f < 50 && e < 50) ? Whe[f * 50 + e] : 0.0f;
        v[u] = (short)f2bf(x);
      }
      wtabE[(nt * 2 + ks) * 64 + l] = v;
    }
}

// ---------------------------------------------------------------------------
// MFMA fused edge-MLP -> attention scores. One block per (b, i, j-chunk of
// 128): 4096 independent blocks, 3 blocks/CU. Weight fragments come from the
// precomputed lane table (20 coalesced 16B loads, L2-resident).
// 256 threads = 4 waves; wave w owns j-rows [w*32, w*32+32).
// scores layout: [b][i][h][j]
// ---------------------------------------------------------------------------
__global__ __launch_bounds__(256, 3) void k_scores_mfma(
    const float* __restrict__ wprob, const float* __restrict__ sloop,
    const s16x8* __restrict__ wtab, const float* __restrict__ betab,
    const float* __restrict__ be2,
    const float* __restrict__ src, const float* __restrict__ dst,
    float* __restrict__ scores)
{
  __shared__ unsigned short wps_s[128][72];    // [j][e] bf16, 18.4 KB
  __shared__ unsigned short hmid_s[128][132];  // [j][f] bf16, 33.8 KB
  __shared__ float masks[128];

  const int blk = blockIdx.x;        // (b*512 + i)*4 + c
  const int c = blk & 3;
  const int i = (blk >> 2) & 511;
  const int b = blk >> 11;
  const int j0c = c << 7;
  const int t = threadIdx.x;
  const int w = t >> 6, l = t & 63;
  const int lr = l & 15, lg = l >> 4;
  const int jbase = w * 32;

  // ---- issue the HBM loads for this chunk FIRST (28 float4/thread) ----
  const size_t rowbase = (size_t)(b * SS + i) * SS * EE + (size_t)c * 6400;
  float4 pw[7], psl[7];
  {
    const float* wp = wprob + rowbase;
    const float* sl = sloop + rowbase;
#pragma unroll
    for (int k = 0; k < 7; ++k)
      if (k < 6 || t < 64) {
        pw[k] = *(const float4*)(wp + 4 * (t + 256 * k));
        psl[k] = *(const float4*)(sl + 4 * (t + 256 * k));
      }
  }

  // ---- weight fragments from lane table (coalesced, L2-resident) ----
  s16x8 wa[2][8];
#pragma unroll
  for (int ks = 0; ks < 2; ++ks)
#pragma unroll
    for (int n = 0; n < 8; ++n) wa[ks][n] = wtab[(ks * 8 + n) * 64 + l];
  s16x8 wb[4];
#pragma unroll
  for (int kk = 0; kk < 4; ++kk) wb[kk] = wtab[(16 + kk) * 64 + l];
  float be1v[8];
#pragma unroll
  for (int n = 0; n < 8; ++n) be1v[n] = betab[n * 64 + l];
  const int hc = (lr < 12) ? lr : 0;
  const float be2v = be2[hc];
  const float srcv = src[((b * HH + hc) << 9) + i];
  const float* drow = dst + ((size_t)(b * HH + hc) << 9);
  float4 dv0 = *(const float4*)(drow + j0c + jbase + lg * 4);
  float4 dv1 = *(const float4*)(drow + j0c + jbase + 16 + lg * 4);

  // zero pad cols e=50..63 (dwords 25..31 of each 36-dword row)
  for (int q = t; q < 896; q += 256) {
    int r = q / 7, cd = 25 + q % 7;
    ((unsigned int*)wps_s)[r * 36 + cd] = 0u;
  }

  // ---- LDS write (waits on wps loads) ----
#pragma unroll
  for (int k = 0; k < 7; ++k)
    if (k < 6 || t < 64) {
      int f = 4 * (t + 256 * k);
      int j = f / 50;
      int e0 = f - j * 50;
      float vs[4] = {pw[k].x + psl[k].x, pw[k].y + psl[k].y,
                     pw[k].z + psl[k].z, pw[k].w + psl[k].w};
#pragma unroll
      for (int u = 0; u < 4; ++u) {
        int e = e0 + u, jj = j;
        if (e >= 50) { e -= 50; jj += 1; }
        wps_s[jj][e] = f2bf(vs[u]);
      }
    }
  __syncthreads();

  // per-wave masks for own j-rows (wave-local write+read; no extra barrier)
  if (l < 32) {
    const unsigned short* row = wps_s[jbase + l];
    float s = 0.0f;
#pragma unroll
    for (int q = 0; q < 6; ++q) {
      s16x8 v = *(const s16x8*)(row + q * 8);
#pragma unroll
      for (int u = 0; u < 8; ++u) s += bf2f((unsigned short)v[u]);
    }
    unsigned int last = *(const unsigned int*)(row + 48);
    s += bf2f((unsigned short)(last & 0xffffu)) + bf2f((unsigned short)(last >> 16));
    masks[jbase + l] = (s == 0.0f) ? 1.0f : 0.0f;
  }

  // ---- stage A: hmid = relu(wps @ We1^T + be1) ----
  f32x4 accA[2][8] = {};
#pragma unroll
  for (int ks = 0; ks < 2; ++ks) {
    s16x8 a0 = *(const s16x8*)&wps_s[jbase + lr][ks * 32 + lg * 8];
    s16x8 a1 = *(const s16x8*)&wps_s[jbase + 16 + lr][ks * 32 + lg * 8];
#pragma unroll
    for (int n = 0; n < 8; ++n) {
      accA[0][n] = __builtin_amdgcn_mfma_f32_16x16x32_bf16(a0, wa[ks][n], accA[0][n], 0, 0, 0);
      accA[1][n] = __builtin_amdgcn_mfma_f32_16x16x32_bf16(a1, wa[ks][n], accA[1][n], 0, 0, 0);
    }
  }
#pragma unroll
  for (int jt = 0; jt < 2; ++jt)
#pragma unroll
    for (int n = 0; n < 8; ++n)
#pragma unroll
      for (int r = 0; r < 4; ++r) {
        float v = fmaxf(accA[jt][n][r] + be1v[n], 0.0f);
        hmid_s[jbase + jt * 16 + lg * 4 + r][n * 16 + lr] = f2bf(v);
      }

  // ---- stage B: A = hmid @ We2^T (wave-local rows; no barrier) ----
  f32x4 accB[2] = {};
#pragma unroll
  for (int kk = 0; kk < 4; ++kk) {
    s16x8 a0 = *(const s16x8*)&hmid_s[jbase + lr][kk * 32 + lg * 8];
    s16x8 a1 = *(const s16x8*)&hmid_s[jbase + 16 + lr][kk * 32 + lg * 8];
    accB[0] = __builtin_amdgcn_mfma_f32_16x16x32_bf16(a0, wb[kk], accB[0], 0, 0, 0);
    accB[1] = __builtin_amdgcn_mfma_f32_16x16x32_bf16(a1, wb[kk], accB[1], 0, 0, 0);
  }

  // ---- epilogue: leaky-relu + mask, direct float4 stores ----
  if (lr < 12) {
#pragma unroll
    for (int jt = 0; jt < 2; ++jt) {
      int jl = jbase + jt * 16 + lg * 4;   // local j of r=0 (4-aligned)
      const float4 dv = jt ? dv1 : dv0;
      float4 st;
#pragma unroll
      for (int r = 0; r < 4; ++r) {
        float x = accB[jt][r] + be2v + srcv + (&dv.x)[r];
        x = (x > 0.0f) ? x : 0.01f * x;
        if (masks[jl + r] != 0.0f) x = -INFINITY;
        (&st.x)[r] = x;
      }
      *(float4*)(scores + ((((size_t)(b * SS + i)) * HH + lr) << 9) + j0c + jl) = st;
    }
  }
}

// ---------------------------------------------------------------------------
// Softmax over j (per b,i,h) + PV: gcnmid[b,i,:] = sum_j attn * feature[b,j,:]
// ---------------------------------------------------------------------------
__global__ __launch_bounds__(256) void k_softmax_pv(
    const float* __restrict__ scores, const float* __restrict__ feat,
    float* __restrict__ gout)
{
  __shared__ float p[2][12][512];
  int blk = blockIdx.x;
  int b = blk >> 8;
  int i0 = (blk & 255) << 1;
  int t = threadIdx.x;
  size_t base = ((size_t)(b * SS + i0) * HH) << 9;
  for (int q = t; q < 12288; q += 256) ((float*)p)[q] = scores[base + q];
  __syncthreads();

  int w = t >> 6, l = t & 63;
  for (int r = w; r < 24; r += 4) {
    int ii = r / 12, h = r % 12;
    float* row = p[ii][h];
    float vv[8];
    float m = -INFINITY;
#pragma unroll
    for (int u = 0; u < 8; ++u) {
      vv[u] = row[l + (u << 6)];
      m = fmaxf(m, vv[u]);
    }
#pragma unroll
    for (int o = 32; o > 0; o >>= 1) m = fmaxf(m, __shfl_xor(m, o));
    float s = 0.0f;
#pragma unroll
    for (int u = 0; u < 8; ++u) {
      float e = __expf(vv[u] - m);
      vv[u] = e;
      s += e;
    }
#pragma unroll
    for (int o = 32; o > 0; o >>= 1) s += __shfl_xor(s, o);
    float inv = 1.0f / s;
#pragma unroll
    for (int u = 0; u < 8; ++u) row[l + (u << 6)] = vv[u] * inv;
  }
  __syncthreads();

  float acc[2][3] = {};
  const float* fb = feat + (size_t)b * SS * DD;
  int h0 = t >> 6;
#pragma unroll 4
  for (int j = 0; j < 512; ++j) {
    const float* fr = fb + (size_t)j * DD;
    float f0 = fr[t], f1 = fr[t + 256], f2 = fr[t + 512];
    float p00 = p[0][h0][j], p10 = p[1][h0][j];
    float p01 = p[0][h0 + 4][j], p11 = p[1][h0 + 4][j];
    float p02 = p[0][h0 + 8][j], p12 = p[1][h0 + 8][j];
    acc[0][0] += p00 * f0; acc[0][1] += p01 * f1; acc[0][2] += p02 * f2;
    acc[1][0] += p10 * f0; acc[1][1] += p11 * f1; acc[1][2] += p12 * f2;
  }
#pragma unroll
  for (int ii = 0; ii < 2; ++ii)
#pragma unroll
    for (int u = 0; u < 3; ++u)
      gout[(size_t)(b * SS + i0 + ii) * DD + t + (u << 8)] = acc[ii][u];
}

// ---------------------------------------------------------------------------
// LayerNorm (torch variant: unbiased std, /(std+eps)) + ReLU -> node (d_out)
// ---------------------------------------------------------------------------
__global__ __launch_bounds__(256) void k_ln(
    const float* __restrict__ gcn2, const float* __restrict__ ga,
    const float* __restrict__ gb, float* __restrict__ out)
{
  __shared__ float rs[4], rss[4];
  int row = blockIdx.x;
  int t = threadIdx.x;
  const float* x = gcn2 + (size_t)row * DD;
  float v[3];
  float s = 0.0f, ss2 = 0.0f;
#pragma unroll
  for (int u = 0; u < 3; ++u) {
    v[u] = x[t + (u << 8)];
    s += v[u];
    ss2 += v[u] * v[u];
  }
#pragma unroll
  for (int o = 32; o > 0; o >>= 1) {
    s += __shfl_down(s, o);
    ss2 += __shfl_down(ss2, o);
  }
  int w = t >> 6, l = t & 63;
  if (l == 0) { rs[w] = s; rss[w] = ss2; }
  __syncthreads();
  float S = rs[0] + rs[1] + rs[2] + rs[3];
  float SSum = rss[0] + rss[1] + rss[2] + rss[3];
  float mean = S * (1.0f / 768.0f);
  float var = (SSum - 768.0f * mean * mean) * (1.0f / 767.0f);
  var = fmaxf(var, 0.0f);
  float rinv = 1.0f / (sqrtf(var) + 1e-6f);
#pragma unroll
  for (int u = 0; u < 3; ++u) {
    int cidx = t + (u << 8);
    float y = ga[cidx] * (v[u] - mean) * rinv + gb[cidx];
    out[(size_t)row * DD + cidx] = fmaxf(y, 0.0f);
  }
}

// ---------------------------------------------------------------------------
// P[b,s,f] = ediag[b,s]@Wh_ei^T + node[b,s]@Wh_n2^T
// Q[b,s,f] = ediag[b,s]@Wh_ej^T + node[b,s]@Wh_n1^T + bh
// Block = 2 rows (grid 512), 256 thr = 4 waves. Lane-resident node frags;
// per output: 3 coalesced float4 weight loads + full-wave shfl reduce.
// ---------------------------------------------------------------------------
__global__ __launch_bounds__(256) void k_pq(
    const float* __restrict__ node, const float* __restrict__ wadj,
    const float* __restrict__ Whei, const float* __restrict__ Whej,
    const float* __restrict__ Whn1, const float* __restrict__ Whn2,
    const float* __restrict__ bh, float* __restrict__ P, float* __restrict__ Q)
{
  __shared__ float nd[2][768];
  __shared__ float ed[2][64];
  const int bs0 = blockIdx.x * 2;
  const int t = threadIdx.x;
  const int w = t >> 6, l = t & 63;

  // stage 2 node rows: 384 float4s total, grid-stride over 256 threads
  for (int q = t; q < 384; q += 256) {
    int rr = q / 192, idx = q % 192;
    *(float4*)(nd[rr] + idx * 4) =
        *(const float4*)(node + (size_t)(bs0 + rr) * DD + idx * 4);
  }
  {
    int rr = t >> 7, tt = t & 127;   // rr=0,1 row; tt element
    if (tt < 50) {
      int bs = bs0 + rr;
      int b = bs >> 9, s = bs & 511;
      ed[rr][tt] = wadj[((size_t)(b * SS + s) * SS + s) * EE + tt];
    }
  }
  __syncthreads();

  // lane-resident node fragments (12 floats per lane per row)
  float4 n00 = *(const float4*)(nd[0] + l * 4);
  float4 n01 = *(const float4*)(nd[0] + 256 + l * 4);
  float4 n02 = *(const float4*)(nd[0] + 512 + l * 4);
  float4 n10 = *(const float4*)(nd[1] + l * 4);
  float4 n11 = *(const float4*)(nd[1] + 256 + l * 4);
  float4 n12 = *(const float4*)(nd[1] + 512 + l * 4);
  float el0 = (l < 50) ? ed[0][l] : 0.0f;
  float el1 = (l < 50) ? ed[1][l] : 0.0f;

  for (int o = w; o < 100; o += 4) {
    const int which = (o >= 50);
    const int f = o - which * 50;
    const float* Wn = which ? Whn1 : Whn2;
    const float* We = which ? Whej : Whei;
    const float* wr = Wn + f * DD;
    float4 w0 = *(const float4*)(wr + l * 4);
    float4 w1 = *(const float4*)(wr + 256 + l * 4);
    float4 w2 = *(const float4*)(wr + 512 + l * 4);
    float wev = (l < 50) ? We[f * EE + l] : 0.0f;
    float a0 = n00.x * w0.x + n00.y * w0.y + n00.z * w0.z + n00.w * w0.w
             + n01.x * w1.x + n01.y * w1.y + n01.z * w1.z + n01.w * w1.w
             + n02.x * w2.x + n02.y * w2.y + n02.z * w2.z + n02.w * w2.w
             + el0 * wev;
    float a1 = n10.x * w0.x + n10.y * w0.y + n10.z * w0.z + n10.w * w0.w
             + n11.x * w1.x + n11.y * w1.y + n11.z * w1.z + n11.w * w1.w
             + n12.x * w2.x + n12.y * w2.y + n12.z * w2.z + n12.w * w2.w
             + el1 * wev;
#pragma unroll
    for (int ofs = 32; ofs > 0; ofs >>= 1) {
      a0 += __shfl_xor(a0, ofs);
      a1 += __shfl_xor(a1, ofs);
    }
    if (l == 0) {
      float bias = which ? bh[f] : 0.0f;
      float* dst0 = (which ? Q : P) + (size_t)bs0 * DE + f;
      dst0[0] = a0 + bias;
      dst0[DE] = a1 + bias;
    }
  }
}

// ---------------------------------------------------------------------------
// MFMA edge refine: edge_out[n,f] = wadj[n,:]@Whe[f,:] + P[b,i,f] + Q[b,j,f]
// ---------------------------------------------------------------------------
__global__ __launch_bounds__(256) void k_edge_mfma(
    const float* __restrict__ wadj, const s16x8* __restrict__ wtabE,
    const float* __restrict__ P, const float* __restrict__ Q,
    float* __restrict__ eout)
{
  __shared__ unsigned short adj_s[128][72];   // [pair][e] bf16, 18.4 KB
  __shared__ float P_s[64];

  const int t = threadIdx.x;
  const size_t n0 = (size_t)blockIdx.x * 128;
  const int b = (int)(n0 >> 18);
  const int i = (int)((n0 & 262143) >> 9);
  const int j0 = (int)(n0 & 511);
  const int w = t >> 6, l = t & 63;
  const int lr = l & 15, lg = l >> 4;
  const int mbase = w * 32;

  // ---- issue wadj tile loads first (7 float4/thread for 6400 floats) ----
  float4 pw[7];
  {
    const float* wp = wadj + n0 * EE;
#pragma unroll
    for (int k = 0; k < 7; ++k)
      if (k < 6 || t < 64) pw[k] = *(const float4*)(wp + 4 * (t + 256 * k));
  }

  // ---- B-fragments from lane table; P row to LDS ----
  s16x8 we[4][2];
#pragma unroll
  for (int nt = 0; nt < 4; ++nt)
#pragma unroll
    for (int ks = 0; ks < 2; ++ks) we[nt][ks] = wtabE[(nt * 2 + ks) * 64 + l];
  if (t < 64) P_s[t] = (t < 50) ? P[(size_t)(b * SS + i) * DE + t] : 0.0f;

  // zero pad cols e=50..63 (dwords 25..31 of each 36-dword row)
  for (int q = t; q < 896; q += 256) {
    int r = q / 7, cd = 25 + q % 7;
    ((unsigned int*)adj_s)[r * 36 + cd] = 0u;
  }

  // ---- LDS write (waits on wadj loads) ----
#pragma unroll
  for (int k = 0; k < 7; ++k)
    if (k < 6 || t < 64) {
      int f = 4 * (t + 256 * k);
      int j = f / 50;
      int e0 = f - j * 50;
#pragma unroll
      for (int u = 0; u < 4; ++u) {
        int e = e0 + u, jj = j;
        if (e >= 50) { e -= 50; jj += 1; }
        adj_s[jj][e] = f2bf((&pw[k].x)[u]);
      }
    }
  __syncthreads();

  // ---- MFMA: [128 x 64(e)] @ [64(e) x 64(f)] ----
  f32x4 acc[2][4] = {};
#pragma unroll
  for (int ks = 0; ks < 2; ++ks) {
    s16x8 a0 = *(const s16x8*)&adj_s[mbase + lr][ks * 32 + lg * 8];
    s16x8 a1 = *(const s16x8*)&adj_s[mbase + 16 + lr][ks * 32 + lg * 8];
#pragma unroll
    for (int nt = 0; nt < 4; ++nt) {
      acc[0][nt] = __builtin_amdgcn_mfma_f32_16x16x32_bf16(a0, we[nt][ks], acc[0][nt], 0, 0, 0);
      acc[1][nt] = __builtin_amdgcn_mfma_f32_16x16x32_bf16(a1, we[nt][ks], acc[1][nt], 0, 0, 0);
    }
  }

  // ---- epilogue: + P[i][f] + Q[j][f], scalar stores (16-lane contiguous) ----
#pragma unroll
  for (int nt = 0; nt < 4; ++nt) {
    int f = nt * 16 + lr;
    if (f < 50) {
      float pf = P_s[f];
#pragma unroll
      for (int mt = 0; mt < 2; ++mt) {
        int m = mbase + mt * 16 + lg * 4;
        const float* qp = Q + (size_t)(b * SS + j0 + m) * DE + f;
        float* op = eout + (n0 + m) * DE + f;
#pragma unroll
        for (int r = 0; r < 4; ++r)
          op[r * DE] = acc[mt][nt][r] + pf + qp[r * DE];
      }
    }
  }
}

// ---------------------------------------------------------------------------
extern "C" void kernel_launch(void* const* d_in, const int* in_sizes, int n_in,
                              void* d_out, int out_size, void* d_ws, size_t ws_size,
                              hipStream_t stream)
{
  const float* wprob = (const float*)d_in[0];
  const float* wadj  = (const float*)d_in[1];
  const float* gin   = (const float*)d_in[2];
  const float* sloop = (const float*)d_in[3];
  const float* W_lin = (const float*)d_in[4];
  const float* b_lin = (const float*)d_in[5];
  const float* fw1   = (const float*)d_in[6];
  const float* fw2   = (const float*)d_in[7];
  const float* We1   = (const float*)d_in[8];
  const float* be1   = (const float*)d_in[9];
  const float* We2   = (const float*)d_in[10];
  const float* be2   = (const float*)d_in[11];
  const float* W_out = (const float*)d_in[12];
  const float* b_out = (const float*)d_in[13];
  const float* ln_a  = (const float*)d_in[14];
  const float* ln_b  = (const float*)d_in[15];
  const float* Whe   = (const float*)d_in[16];
  const float* Whei  = (const float*)d_in[17];
  const float* Whej  = (const float*)d_in[18];
  const float* Whn1  = (const float*)d_in[19];
  const float* Whn2  = (const float*)d_in[20];
  const float* bh    = (const float*)d_in[21];

  float* ws = (float*)d_ws;
  float* feature = ws + 0;         // [B,S,D]      786432
  float* src     = ws + 786432;    // [B,H,S]      12288
  float* dst     = ws + 798720;    // [B,H,S]      12288
  float* scores  = ws + 811008;    // [B,S,H,S]    6291456
  float* gcnmid  = ws + 7102464;   // [B,S,D]      786432
  float* gcn2    = ws + 7888896;   // [B,S,D]      786432
  float* P       = ws + 8675328;   // [B,S,DE]     51200
  float* Q       = ws + 8726528;   // [B,S,DE]     51200
  s16x8* wtab    = (s16x8*)(ws + 8777728);  // 20*64 frags = 5120 floats
  float* betab   = ws + 8782848;   // 8*64 = 512 floats
  s16x8* wtabE   = (s16x8*)(ws + 8783360);  // 8*64 frags = 2048 floats

  float* node = (float*)d_out;            // output 0: [B,S,D]
  float* eout = (float*)d_out + 786432;   // output 1: [B,S,S,DE]

  k_prep<<<1, 64, 0, stream>>>(We1, be1, We2, Whe, wtab, betab, wtabE);
  k_gemm_bias<<<dim3(DD / 64, (BB * SS) / 64), 256, 0, stream>>>(
      gin, DD, W_lin, b_lin, feature, DD, BB * SS, DD, DD);
  k_attnvec<<<BB * SS, 192, 0, stream>>>(feature, fw1, fw2, src, dst);
  k_scores_mfma<<<BB * SS * 4, 256, 0, stream>>>(
      wprob, sloop, wtab, betab, be2, src, dst, scores);
  k_softmax_pv<<<BB * SS / 2, 256, 0, stream>>>(scores, feature, gcnmid);
  k_gemm_bias<<<dim3(DD / 64, (BB * SS) / 64), 256, 0, stream>>>(
      gcnmid, DD, W_out, b_out, gcn2, DD, BB * SS, DD, DD);
  k_ln<<<BB * SS, 256, 0, stream>>>(gcn2, ln_a, ln_b, node);
  k_pq<<<BB * SS / 2, 256, 0, stream>>>(node, wadj, Whei, Whej, Whn1, Whn2, bh, P, Q);
  k_edge_mfma<<<(BB * SS * SS) / 128, 256, 0, stream>>>(wadj, wtabE, P, Q, eout);
}

// Round 9
// 284.228 us; speedup vs baseline: 2.1473x; 1.0631x over previous
//
#include <hip/hip_runtime.h>
#include <math.h>
#include <stddef.h>

// Problem constants
#define BB 2
#define SS 512
#define DD 768
#define HH 12
#define HDIM 64
#define EE 50
#define DE 50
#define F1 128

typedef float f32x4 __attribute__((ext_vector_type(4)));
typedef short s16x8 __attribute__((ext_vector_type(8)));

// f32 -> bf16 bits, round-to-nearest-even
static __device__ __forceinline__ unsigned short f2bf(float x) {
  unsigned int u = __float_as_uint(x);
  unsigned int r = u + 0x7fffu + ((u >> 16) & 1u);
  return (unsigned short)(r >> 16);
}
static __device__ __forceinline__ float bf2f(unsigned short b) {
  return __uint_as_float(((unsigned int)b) << 16);
}

// ---------------------------------------------------------------------------
// Generic tiled f32 GEMM: Y[m][n] = sum_k X[m][k] * W[n][k] + bias[n]
// ---------------------------------------------------------------------------
__global__ __launch_bounds__(256) void k_gemm_bias(
    const float* __restrict__ X, int ldx,
    const float* __restrict__ W,   // [N][K] row-major
    const float* __restrict__ bias,
    float* __restrict__ Y, int ldy,
    int M, int N, int K)
{
  __shared__ float Xs[32][68];
  __shared__ float Ws[32][68];
  int t = threadIdx.x;
  int tx = t & 15, ty = t >> 4;
  int m0 = blockIdx.y * 64, n0 = blockIdx.x * 64;
  float acc[4][4] = {};
  for (int k0 = 0; k0 < K; k0 += 32) {
#pragma unroll
    for (int q = 0; q < 2; ++q) {
      int idx = t + q * 256;
      int r = idx >> 3, c = (idx & 7) << 2;
      float4 v = *(const float4*)(X + (size_t)(m0 + r) * ldx + k0 + c);
      Xs[c + 0][r] = v.x; Xs[c + 1][r] = v.y; Xs[c + 2][r] = v.z; Xs[c + 3][r] = v.w;
      float4 w = *(const float4*)(W + (size_t)(n0 + r) * K + k0 + c);
      Ws[c + 0][r] = w.x; Ws[c + 1][r] = w.y; Ws[c + 2][r] = w.z; Ws[c + 3][r] = w.w;
    }
    __syncthreads();
#pragma unroll
    for (int kk = 0; kk < 32; ++kk) {
      float a[4], b[4];
#pragma unroll
      for (int u = 0; u < 4; ++u) a[u] = Xs[kk][ty * 4 + u];
#pragma unroll
      for (int u = 0; u < 4; ++u) b[u] = Ws[kk][tx * 4 + u];
#pragma unroll
      for (int i = 0; i < 4; ++i)
#pragma unroll
        for (int j = 0; j < 4; ++j) acc[i][j] += a[i] * b[j];
    }
    __syncthreads();
  }
#pragma unroll
  for (int i = 0; i < 4; ++i) {
    int m = m0 + ty * 4 + i;
#pragma unroll
    for (int j = 0; j < 4; ++j) {
      int n = n0 + tx * 4 + j;
      Y[(size_t)m * ldy + n] = acc[i][j] + bias[n];
    }
  }
}

// ---------------------------------------------------------------------------
// attn_src[b,h,s], attn_dst[b,h,s]
// ---------------------------------------------------------------------------
__global__ __launch_bounds__(192) void k_attnvec(
    const float* __restrict__ feat, const float* __restrict__ w1,
    const float* __restrict__ w2, float* __restrict__ src, float* __restrict__ dst)
{
  int bs = blockIdx.x;
  int t = threadIdx.x;
  int h = t >> 4, l = t & 15;
  float4 f = *(const float4*)(feat + (size_t)bs * DD + h * HDIM + l * 4);
  float4 a = *(const float4*)(w1 + h * HDIM + l * 4);
  float4 c = *(const float4*)(w2 + h * HDIM + l * 4);
  float ps = f.x * a.x + f.y * a.y + f.z * a.z + f.w * a.w;
  float pd = f.x * c.x + f.y * c.y + f.z * c.z + f.w * c.w;
#pragma unroll
  for (int o = 8; o > 0; o >>= 1) {
    ps += __shfl_xor(ps, o);
    pd += __shfl_xor(pd, o);
  }
  if (l == 0) {
    int b = bs >> 9, s = bs & 511;
    src[((b * HH + h) << 9) + s] = ps;
    dst[((b * HH + h) << 9) + s] = pd;
  }
}

// ---------------------------------------------------------------------------
// Precompute per-lane MFMA weight fragments (lane-only dependent, 64 variants)
// wtab[k][lane] : s16x8;  k = ks*8+n (We1 frags, 0..15), 16+kk (We2, 16..19)
// betab[n][lane]: f32     be1[n*16 + (lane&15)]
// wtabE[nt*2+ks][lane]: Whe B-frags for the edge GEMM (f=nt*16+lr, e=ks*32+..)
// ---------------------------------------------------------------------------
__global__ __launch_bounds__(64) void k_prep(
    const float* __restrict__ We1, const float* __restrict__ be1,
    const float* __restrict__ We2, const float* __restrict__ Whe,
    s16x8* __restrict__ wtab, float* __restrict__ betab,
    s16x8* __restrict__ wtabE)
{
  const int l = threadIdx.x;
  const int lr = l & 15, lg = l >> 4;
#pragma unroll
  for (int ks = 0; ks < 2; ++ks)
#pragma unroll
    for (int n = 0; n < 8; ++n) {
      s16x8 v;
#pragma unroll
      for (int u = 0; u < 8; ++u) {
        int e = ks * 32 + lg * 8 + u;
        float x = (e < 50) ? We1[(n * 16 + lr) * 50 + e] : 0.0f;
        v[u] = (short)f2bf(x);
      }
      wtab[(ks * 8 + n) * 64 + l] = v;
    }
#pragma unroll
  for (int kk = 0; kk < 4; ++kk) {
    s16x8 v;
#pragma unroll
    for (int u = 0; u < 8; ++u) {
      int f = kk * 32 + lg * 8 + u;
      v[u] = (short)((lr < 12) ? f2bf(We2[lr * 128 + f]) : (unsigned short)0);
    }
    wtab[(16 + kk) * 64 + l] = v;
  }
#pragma unroll
  for (int n = 0; n < 8; ++n) betab[n * 64 + l] = be1[n * 16 + lr];
#pragma unroll
  for (int nt = 0; nt < 4; ++nt)
#pragma unroll
    for (int ks = 0; ks < 2; ++ks) {
      int f = nt * 16 + lr;
      s16x8 v;
#pragma unroll
      for (int u = 0; u < 8; ++u) {
        int e = ks * 32 + lg * 8 + u;
        float x = (f < 50 && e < 50) ? Whe[f * 50 + e] : 0.0f;
        v[u] = (short)f2bf(x);
      }
      wtabE[(nt * 2 + ks) * 64 + l] = v;
    }
}

// ---------------------------------------------------------------------------
// MFMA fused edge-MLP -> attention scores. One block per (b, i, j-chunk of
// 128). Stage A runs in TWO f-halves sharing one half-width hmid buffer
// (wave-private write->read, in-order LDS): LDS 37.4 KB -> 4 blocks/CU.
// 256 threads = 4 waves; wave w owns j-rows [w*32, w*32+32).
// scores layout: [b][i][h][j]
// ---------------------------------------------------------------------------
__global__ __launch_bounds__(256, 4) void k_scores_mfma(
    const float* __restrict__ wprob, const float* __restrict__ sloop,
    const s16x8* __restrict__ wtab, const float* __restrict__ betab,
    const float* __restrict__ be2,
    const float* __restrict__ src, const float* __restrict__ dst,
    float* __restrict__ scores)
{
  __shared__ unsigned short wps_s[128][72];   // [j][e] bf16, 18.4 KB
  __shared__ unsigned short hmid_s[128][72];  // [j][f-half] bf16, 18.4 KB
  __shared__ float masks[128];

  const int blk = blockIdx.x;        // (b*512 + i)*4 + c
  const int c = blk & 3;
  const int i = (blk >> 2) & 511;
  const int b = blk >> 11;
  const int j0c = c << 7;
  const int t = threadIdx.x;
  const int w = t >> 6, l = t & 63;
  const int lr = l & 15, lg = l >> 4;
  const int jbase = w * 32;

  // ---- issue the HBM loads for this chunk FIRST (28 float4/thread) ----
  const size_t rowbase = (size_t)(b * SS + i) * SS * EE + (size_t)c * 6400;
  float4 pw[7], psl[7];
  {
    const float* wp = wprob + rowbase;
    const float* sl = sloop + rowbase;
#pragma unroll
    for (int k = 0; k < 7; ++k)
      if (k < 6 || t < 64) {
        pw[k] = *(const float4*)(wp + 4 * (t + 256 * k));
        psl[k] = *(const float4*)(sl + 4 * (t + 256 * k));
      }
  }

  // ---- We2 fragments + biases (We1 frags loaded per-half later) ----
  s16x8 wb[4];
#pragma unroll
  for (int kk = 0; kk < 4; ++kk) wb[kk] = wtab[(16 + kk) * 64 + l];
  float be1v[8];
#pragma unroll
  for (int n = 0; n < 8; ++n) be1v[n] = betab[n * 64 + l];
  const int hc = (lr < 12) ? lr : 0;
  const float be2v = be2[hc];
  const float srcv = src[((b * HH + hc) << 9) + i];
  const float* drow = dst + ((size_t)(b * HH + hc) << 9);
  float4 dv0 = *(const float4*)(drow + j0c + jbase + lg * 4);
  float4 dv1 = *(const float4*)(drow + j0c + jbase + 16 + lg * 4);

  // zero pad cols e=50..63 (dwords 25..31 of each 36-dword row)
  for (int q = t; q < 896; q += 256) {
    int r = q / 7, cd = 25 + q % 7;
    ((unsigned int*)wps_s)[r * 36 + cd] = 0u;
  }

  // ---- LDS write (waits on wps loads) ----
#pragma unroll
  for (int k = 0; k < 7; ++k)
    if (k < 6 || t < 64) {
      int f = 4 * (t + 256 * k);
      int j = f / 50;
      int e0 = f - j * 50;
      float vs[4] = {pw[k].x + psl[k].x, pw[k].y + psl[k].y,
                     pw[k].z + psl[k].z, pw[k].w + psl[k].w};
#pragma unroll
      for (int u = 0; u < 4; ++u) {
        int e = e0 + u, jj = j;
        if (e >= 50) { e -= 50; jj += 1; }
        wps_s[jj][e] = f2bf(vs[u]);
      }
    }
  __syncthreads();

  // per-wave masks for own j-rows (wave-local write+read; no extra barrier)
  if (l < 32) {
    const unsigned short* row = wps_s[jbase + l];
    float s = 0.0f;
#pragma unroll
    for (int q = 0; q < 6; ++q) {
      s16x8 v = *(const s16x8*)(row + q * 8);
#pragma unroll
      for (int u = 0; u < 8; ++u) s += bf2f((unsigned short)v[u]);
    }
    unsigned int last = *(const unsigned int*)(row + 48);
    s += bf2f((unsigned short)(last & 0xffffu)) + bf2f((unsigned short)(last >> 16));
    masks[jbase + l] = (s == 0.0f) ? 1.0f : 0.0f;
  }

  // ---- A-fragments from wps (read once, reused by both halves) ----
  s16x8 aA[2][2];   // [jt][ks]
#pragma unroll
  for (int ks = 0; ks < 2; ++ks) {
    aA[0][ks] = *(const s16x8*)&wps_s[jbase + lr][ks * 32 + lg * 8];
    aA[1][ks] = *(const s16x8*)&wps_s[jbase + 16 + lr][ks * 32 + lg * 8];
  }

  f32x4 accB[2] = {};
#pragma unroll
  for (int h = 0; h < 2; ++h) {
    // We1 fragments for this half (f in [64h, 64h+64))
    s16x8 wah[2][4];
#pragma unroll
    for (int ks = 0; ks < 2; ++ks)
#pragma unroll
      for (int nn = 0; nn < 4; ++nn)
        wah[ks][nn] = wtab[(ks * 8 + h * 4 + nn) * 64 + l];

    // stage A (half): hmid_half = relu(wps @ We1^T + be1)
    f32x4 accA[2][4] = {};
#pragma unroll
    for (int ks = 0; ks < 2; ++ks)
#pragma unroll
      for (int nn = 0; nn < 4; ++nn) {
        accA[0][nn] = __builtin_amdgcn_mfma_f32_16x16x32_bf16(aA[0][ks], wah[ks][nn], accA[0][nn], 0, 0, 0);
        accA[1][nn] = __builtin_amdgcn_mfma_f32_16x16x32_bf16(aA[1][ks], wah[ks][nn], accA[1][nn], 0, 0, 0);
      }
#pragma unroll
    for (int jt = 0; jt < 2; ++jt)
#pragma unroll
      for (int nn = 0; nn < 4; ++nn)
#pragma unroll
        for (int r = 0; r < 4; ++r) {
          float v = fmaxf(accA[jt][nn][r] + be1v[h * 4 + nn], 0.0f);
          hmid_s[jbase + jt * 16 + lg * 4 + r][nn * 16 + lr] = f2bf(v);
        }

    // stage B partial over this half's K-range (wave-private rows; in-order
    // LDS per wave makes write->read and next-half overwrite safe)
#pragma unroll
    for (int kh = 0; kh < 2; ++kh) {
      int kk = 2 * h + kh;
      s16x8 a0 = *(const s16x8*)&hmid_s[jbase + lr][kh * 32 + lg * 8];
      s16x8 a1 = *(const s16x8*)&hmid_s[jbase + 16 + lr][kh * 32 + lg * 8];
      accB[0] = __builtin_amdgcn_mfma_f32_16x16x32_bf16(a0, wb[kk], accB[0], 0, 0, 0);
      accB[1] = __builtin_amdgcn_mfma_f32_16x16x32_bf16(a1, wb[kk], accB[1], 0, 0, 0);
    }
  }

  // ---- epilogue: leaky-relu + mask, direct float4 stores ----
  if (lr < 12) {
#pragma unroll
    for (int jt = 0; jt < 2; ++jt) {
      int jl = jbase + jt * 16 + lg * 4;   // local j of r=0 (4-aligned)
      const float4 dv = jt ? dv1 : dv0;
      float4 st;
#pragma unroll
      for (int r = 0; r < 4; ++r) {
        float x = accB[jt][r] + be2v + srcv + (&dv.x)[r];
        x = (x > 0.0f) ? x : 0.01f * x;
        if (masks[jl + r] != 0.0f) x = -INFINITY;
        (&st.x)[r] = x;
      }
      *(float4*)(scores + ((((size_t)(b * SS + i)) * HH + lr) << 9) + j0c + jl) = st;
    }
  }
}

// ---------------------------------------------------------------------------
// Softmax over j (per b,i,h) + PV: gcnmid[b,i,:] = sum_j attn * feature[b,j,:]
// ---------------------------------------------------------------------------
__global__ __launch_bounds__(256) void k_softmax_pv(
    const float* __restrict__ scores, const float* __restrict__ feat,
    float* __restrict__ gout)
{
  __shared__ float p[2][12][512];
  int blk = blockIdx.x;
  int b = blk >> 8;
  int i0 = (blk & 255) << 1;
  int t = threadIdx.x;
  size_t base = ((size_t)(b * SS + i0) * HH) << 9;
  for (int q = t; q < 12288; q += 256) ((float*)p)[q] = scores[base + q];
  __syncthreads();

  int w = t >> 6, l = t & 63;
  for (int r = w; r < 24; r += 4) {
    int ii = r / 12, h = r % 12;
    float* row = p[ii][h];
    float vv[8];
    float m = -INFINITY;
#pragma unroll
    for (int u = 0; u < 8; ++u) {
      vv[u] = row[l + (u << 6)];
      m = fmaxf(m, vv[u]);
    }
#pragma unroll
    for (int o = 32; o > 0; o >>= 1) m = fmaxf(m, __shfl_xor(m, o));
    float s = 0.0f;
#pragma unroll
    for (int u = 0; u < 8; ++u) {
      float e = __expf(vv[u] - m);
      vv[u] = e;
      s += e;
    }
#pragma unroll
    for (int o = 32; o > 0; o >>= 1) s += __shfl_xor(s, o);
    float inv = 1.0f / s;
#pragma unroll
    for (int u = 0; u < 8; ++u) row[l + (u << 6)] = vv[u] * inv;
  }
  __syncthreads();

  float acc[2][3] = {};
  const float* fb = feat + (size_t)b * SS * DD;
  int h0 = t >> 6;
#pragma unroll 4
  for (int j = 0; j < 512; ++j) {
    const float* fr = fb + (size_t)j * DD;
    float f0 = fr[t], f1 = fr[t + 256], f2 = fr[t + 512];
    float p00 = p[0][h0][j], p10 = p[1][h0][j];
    float p01 = p[0][h0 + 4][j], p11 = p[1][h0 + 4][j];
    float p02 = p[0][h0 + 8][j], p12 = p[1][h0 + 8][j];
    acc[0][0] += p00 * f0; acc[0][1] += p01 * f1; acc[0][2] += p02 * f2;
    acc[1][0] += p10 * f0; acc[1][1] += p11 * f1; acc[1][2] += p12 * f2;
  }
#pragma unroll
  for (int ii = 0; ii < 2; ++ii)
#pragma unroll
    for (int u = 0; u < 3; ++u)
      gout[(size_t)(b * SS + i0 + ii) * DD + t + (u << 8)] = acc[ii][u];
}

// ---------------------------------------------------------------------------
// LayerNorm (torch variant: unbiased std, /(std+eps)) + ReLU -> node (d_out)
// ---------------------------------------------------------------------------
__global__ __launch_bounds__(256) void k_ln(
    const float* __restrict__ gcn2, const float* __restrict__ ga,
    const float* __restrict__ gb, float* __restrict__ out)
{
  __shared__ float rs[4], rss[4];
  int row = blockIdx.x;
  int t = threadIdx.x;
  const float* x = gcn2 + (size_t)row * DD;
  float v[3];
  float s = 0.0f, ss2 = 0.0f;
#pragma unroll
  for (int u = 0; u < 3; ++u) {
    v[u] = x[t + (u << 8)];
    s += v[u];
    ss2 += v[u] * v[u];
  }
#pragma unroll
  for (int o = 32; o > 0; o >>= 1) {
    s += __shfl_down(s, o);
    ss2 += __shfl_down(ss2, o);
  }
  int w = t >> 6, l = t & 63;
  if (l == 0) { rs[w] = s; rss[w] = ss2; }
  __syncthreads();
  float S = rs[0] + rs[1] + rs[2] + rs[3];
  float SSum = rss[0] + rss[1] + rss[2] + rss[3];
  float mean = S * (1.0f / 768.0f);
  float var = (SSum - 768.0f * mean * mean) * (1.0f / 767.0f);
  var = fmaxf(var, 0.0f);
  float rinv = 1.0f / (sqrtf(var) + 1e-6f);
#pragma unroll
  for (int u = 0; u < 3; ++u) {
    int cidx = t + (u << 8);
    float y = ga[cidx] * (v[u] - mean) * rinv + gb[cidx];
    out[(size_t)row * DD + cidx] = fmaxf(y, 0.0f);
  }
}

// ---------------------------------------------------------------------------
// P[b,s,f] = ediag[b,s]@Wh_ei^T + node[b,s]@Wh_n2^T
// Q[b,s,f] = ediag[b,s]@Wh_ej^T + node[b,s]@Wh_n1^T + bh
// Block = 2 rows (grid 512), 256 thr = 4 waves. Lane-resident node frags;
// per output: 3 coalesced float4 weight loads + full-wave shfl reduce.
// ---------------------------------------------------------------------------
__global__ __launch_bounds__(256) void k_pq(
    const float* __restrict__ node, const float* __restrict__ wadj,
    const float* __restrict__ Whei, const float* __restrict__ Whej,
    const float* __restrict__ Whn1, const float* __restrict__ Whn2,
    const float* __restrict__ bh, float* __restrict__ P, float* __restrict__ Q)
{
  __shared__ float nd[2][768];
  __shared__ float ed[2][64];
  const int bs0 = blockIdx.x * 2;
  const int t = threadIdx.x;
  const int w = t >> 6, l = t & 63;

  // stage 2 node rows: 384 float4s total, grid-stride over 256 threads
  for (int q = t; q < 384; q += 256) {
    int rr = q / 192, idx = q % 192;
    *(float4*)(nd[rr] + idx * 4) =
        *(const float4*)(node + (size_t)(bs0 + rr) * DD + idx * 4);
  }
  {
    int rr = t >> 7, tt = t & 127;   // rr=0,1 row; tt element
    if (tt < 50) {
      int bs = bs0 + rr;
      int b = bs >> 9, s = bs & 511;
      ed[rr][tt] = wadj[((size_t)(b * SS + s) * SS + s) * EE + tt];
    }
  }
  __syncthreads();

  // lane-resident node fragments (12 floats per lane per row)
  float4 n00 = *(const float4*)(nd[0] + l * 4);
  float4 n01 = *(const float4*)(nd[0] + 256 + l * 4);
  float4 n02 = *(const float4*)(nd[0] + 512 + l * 4);
  float4 n10 = *(const float4*)(nd[1] + l * 4);
  float4 n11 = *(const float4*)(nd[1] + 256 + l * 4);
  float4 n12 = *(const float4*)(nd[1] + 512 + l * 4);
  float el0 = (l < 50) ? ed[0][l] : 0.0f;
  float el1 = (l < 50) ? ed[1][l] : 0.0f;

  for (int o = w; o < 100; o += 4) {
    const int which = (o >= 50);
    const int f = o - which * 50;
    const float* Wn = which ? Whn1 : Whn2;
    const float* We = which ? Whej : Whei;
    const float* wr = Wn + f * DD;
    float4 w0 = *(const float4*)(wr + l * 4);
    float4 w1 = *(const float4*)(wr + 256 + l * 4);
    float4 w2 = *(const float4*)(wr + 512 + l * 4);
    float wev = (l < 50) ? We[f * EE + l] : 0.0f;
    float a0 = n00.x * w0.x + n00.y * w0.y + n00.z * w0.z + n00.w * w0.w
             + n01.x * w1.x + n01.y * w1.y + n01.z * w1.z + n01.w * w1.w
             + n02.x * w2.x + n02.y * w2.y + n02.z * w2.z + n02.w * w2.w
             + el0 * wev;
    float a1 = n10.x * w0.x + n10.y * w0.y + n10.z * w0.z + n10.w * w0.w
             + n11.x * w1.x + n11.y * w1.y + n11.z * w1.z + n11.w * w1.w
             + n12.x * w2.x + n12.y * w2.y + n12.z * w2.z + n12.w * w2.w
             + el1 * wev;
#pragma unroll
    for (int ofs = 32; ofs > 0; ofs >>= 1) {
      a0 += __shfl_xor(a0, ofs);
      a1 += __shfl_xor(a1, ofs);
    }
    if (l == 0) {
      float bias = which ? bh[f] : 0.0f;
      float* dst0 = (which ? Q : P) + (size_t)bs0 * DE + f;
      dst0[0] = a0 + bias;
      dst0[DE] = a1 + bias;
    }
  }
}

// ---------------------------------------------------------------------------
// MFMA edge refine: edge_out[n,f] = wadj[n,:]@Whe[f,:] + P[b,i,f] + Q[b,j,f]
// Result parked in LDS (aliasing adj_s after a barrier) -> float4 stream out.
// ---------------------------------------------------------------------------
__global__ __launch_bounds__(256) void k_edge_mfma(
    const float* __restrict__ wadj, const s16x8* __restrict__ wtabE,
    const float* __restrict__ P, const float* __restrict__ Q,
    float* __restrict__ eout)
{
  __shared__ __align__(16) unsigned char raw[25600];  // max(adj_s, park tile)
  unsigned short (*adj_s)[72] = (unsigned short(*)[72])raw;  // 18432 B
  float* park = (float*)raw;                                 // 6400 f32
  __shared__ float P_s[64];

  const int t = threadIdx.x;
  const size_t n0 = (size_t)blockIdx.x * 128;
  const int b = (int)(n0 >> 18);
  const int i = (int)((n0 & 262143) >> 9);
  const int j0 = (int)(n0 & 511);
  const int w = t >> 6, l = t & 63;
  const int lr = l & 15, lg = l >> 4;
  const int mbase = w * 32;

  // ---- issue wadj tile loads first (7 float4/thread for 6400 floats) ----
  float4 pw[7];
  {
    const float* wp = wadj + n0 * EE;
#pragma unroll
    for (int k = 0; k < 7; ++k)
      if (k < 6 || t < 64) pw[k] = *(const float4*)(wp + 4 * (t + 256 * k));
  }

  // ---- B-fragments from lane table; P row to LDS ----
  s16x8 we[4][2];
#pragma unroll
  for (int nt = 0; nt < 4; ++nt)
#pragma unroll
    for (int ks = 0; ks < 2; ++ks) we[nt][ks] = wtabE[(nt * 2 + ks) * 64 + l];
  if (t < 64) P_s[t] = (t < 50) ? P[(size_t)(b * SS + i) * DE + t] : 0.0f;

  // zero pad cols e=50..63 (dwords 25..31 of each 36-dword row)
  for (int q = t; q < 896; q += 256) {
    int r = q / 7, cd = 25 + q % 7;
    ((unsigned int*)adj_s)[r * 36 + cd] = 0u;
  }

  // ---- LDS write (waits on wadj loads) ----
#pragma unroll
  for (int k = 0; k < 7; ++k)
    if (k < 6 || t < 64) {
      int f = 4 * (t + 256 * k);
      int j = f / 50;
      int e0 = f - j * 50;
#pragma unroll
      for (int u = 0; u < 4; ++u) {
        int e = e0 + u, jj = j;
        if (e >= 50) { e -= 50; jj += 1; }
        adj_s[jj][e] = f2bf((&pw[k].x)[u]);
      }
    }
  __syncthreads();

  // ---- MFMA: [128 x 64(e)] @ [64(e) x 64(f)] ----
  f32x4 acc[2][4] = {};
#pragma unroll
  for (int ks = 0; ks < 2; ++ks) {
    s16x8 a0 = *(const s16x8*)&adj_s[mbase + lr][ks * 32 + lg * 8];
    s16x8 a1 = *(const s16x8*)&adj_s[mbase + 16 + lr][ks * 32 + lg * 8];
#pragma unroll
    for (int nt = 0; nt < 4; ++nt) {
      acc[0][nt] = __builtin_amdgcn_mfma_f32_16x16x32_bf16(a0, we[nt][ks], acc[0][nt], 0, 0, 0);
      acc[1][nt] = __builtin_amdgcn_mfma_f32_16x16x32_bf16(a1, we[nt][ks], acc[1][nt], 0, 0, 0);
    }
  }
  __syncthreads();  // all waves done reading adj_s -> reuse as park tile

  // ---- epilogue: + P[i][f] + Q[j][f] -> park[m][f] ----
#pragma unroll
  for (int nt = 0; nt < 4; ++nt) {
    int f = nt * 16 + lr;
    if (f < 50) {
      float pf = P_s[f];
#pragma unroll
      for (int mt = 0; mt < 2; ++mt) {
        int m = mbase + mt * 16 + lg * 4;
        const float* qp = Q + (size_t)(b * SS + j0 + m) * DE + f;
#pragma unroll
        for (int r = 0; r < 4; ++r)
          park[(m + r) * DE + f] = acc[mt][nt][r] + pf + qp[r * DE];
      }
    }
  }
  __syncthreads();

  // ---- stream out: 1600 float4, fully coalesced ----
  const float4* s4 = (const float4*)park;
  float4* d4 = (float4*)(eout + n0 * DE);
  for (int q = t; q < 1600; q += 256) d4[q] = s4[q];
}

// ---------------------------------------------------------------------------
extern "C" void kernel_launch(void* const* d_in, const int* in_sizes, int n_in,
                              void* d_out, int out_size, void* d_ws, size_t ws_size,
                              hipStream_t stream)
{
  const float* wprob = (const float*)d_in[0];
  const float* wadj  = (const float*)d_in[1];
  const float* gin   = (const float*)d_in[2];
  const float* sloop = (const float*)d_in[3];
  const float* W_lin = (const float*)d_in[4];
  const float* b_lin = (const float*)d_in[5];
  const float* fw1   = (const float*)d_in[6];
  const float* fw2   = (const float*)d_in[7];
  const float* We1   = (const float*)d_in[8];
  const float* be1   = (const float*)d_in[9];
  const float* We2   = (const float*)d_in[10];
  const float* be2   = (const float*)d_in[11];
  const float* W_out = (const float*)d_in[12];
  const float* b_out = (const float*)d_in[13];
  const float* ln_a  = (const float*)d_in[14];
  const float* ln_b  = (const float*)d_in[15];
  const float* Whe   = (const float*)d_in[16];
  const float* Whei  = (const float*)d_in[17];
  const float* Whej  = (const float*)d_in[18];
  const float* Whn1  = (const float*)d_in[19];
  const float* Whn2  = (const float*)d_in[20];
  const float* bh    = (const float*)d_in[21];

  float* ws = (float*)d_ws;
  float* feature = ws + 0;         // [B,S,D]      786432
  float* src     = ws + 786432;    // [B,H,S]      12288
  float* dst     = ws + 798720;    // [B,H,S]      12288
  float* scores  = ws + 811008;    // [B,S,H,S]    6291456
  float* gcnmid  = ws + 7102464;   // [B,S,D]      786432
  float* gcn2    = ws + 7888896;   // [B,S,D]      786432
  float* P       = ws + 8675328;   // [B,S,DE]     51200
  float* Q       = ws + 8726528;   // [B,S,DE]     51200
  s16x8* wtab    = (s16x8*)(ws + 8777728);  // 20*64 frags = 5120 floats
  float* betab   = ws + 8782848;   // 8*64 = 512 floats
  s16x8* wtabE   = (s16x8*)(ws + 8783360);  // 8*64 frags = 2048 floats

  float* node = (float*)d_out;            // output 0: [B,S,D]
  float* eout = (float*)d_out + 786432;   // output 1: [B,S,S,DE]

  k_prep<<<1, 64, 0, stream>>>(We1, be1, We2, Whe, wtab, betab, wtabE);
  k_gemm_bias<<<dim3(DD / 64, (BB * SS) / 64), 256, 0, stream>>>(
      gin, DD, W_lin, b_lin, feature, DD, BB * SS, DD, DD);
  k_attnvec<<<BB * SS, 192, 0, stream>>>(feature, fw1, fw2, src, dst);
  k_scores_mfma<<<BB * SS * 4, 256, 0, stream>>>(
      wprob, sloop, wtab, betab, be2, src, dst, scores);
  k_softmax_pv<<<BB * SS / 2, 256, 0, stream>>>(scores, feature, gcnmid);
  k_gemm_bias<<<dim3(DD / 64, (BB * SS) / 64), 256, 0, stream>>>(
      gcnmid, DD, W_out, b_out, gcn2, DD, BB * SS, DD, DD);
  k_ln<<<BB * SS, 256, 0, stream>>>(gcn2, ln_a, ln_b, node);
  k_pq<<<BB * SS / 2, 256, 0, stream>>>(node, wadj, Whei, Whej, Whn1, Whn2, bh, P, Q);
  k_edge_mfma<<<(BB * SS * SS) / 128, 256, 0, stream>>>(wadj, wtabE, P, Q, eout);
}